// Round 18
// baseline (278.383 us; speedup 1.0000x reference)
//
#include <hip/hip_runtime.h>
#include <hip/hip_bf16.h>
#include <math.h>

#define NHEAD 16
#define SEQ 1025
#define BATCH 2
#define NH2 32
#define KSCALE (1.0f/48.0f)
#define QSCALE (KSCALE * 1.4426950408889634f)   // fold log2(e): exp(|S|)=exp2(|S'|)
#define EPS_RMS 1.1920929e-07f
#define EPS_HEAD 1e-05f
#define LAMBDA_INIT 0.2f
#define R_TOT (BATCH*SEQ)
#define NVT 17              // V tiles per head (ceil(SEQ/64))

typedef __attribute__((ext_vector_type(8))) short bf16x8;
typedef __attribute__((ext_vector_type(4))) float f32x4;
typedef __attribute__((ext_vector_type(4))) int  i32x4;

static __device__ __forceinline__ unsigned short f2bf(float x) {
    unsigned int u = __float_as_uint(x);
    unsigned int r = (u + 0x7fffu + ((u >> 16) & 1u)) >> 16;
    return (unsigned short)r;
}
static __device__ __forceinline__ float bf2f(unsigned short h) {
    return __uint_as_float(((unsigned int)h) << 16);
}
static __device__ __forceinline__ void split3(float v, unsigned short& h,
                                              unsigned short& m, unsigned short& l) {
    h = f2bf(v); float r1 = v - bf2f(h);
    m = f2bf(r1); float r2 = r1 - bf2f(m);
    l = f2bf(r2);
}
static __device__ __forceinline__ f32x4 MFMA(bf16x8 a, bf16x8 b, f32x4 c) {
    return __builtin_amdgcn_mfma_f32_16x16x32_bf16(a, b, c, 0, 0, 0);
}
// async global->LDS, 16B per lane; LDS dest = wave-uniform base + lane*16
static __device__ __forceinline__ void gl16(const unsigned short* g,
                                            unsigned short* l) {
    __builtin_amdgcn_global_load_lds(
        (const __attribute__((address_space(1))) void*)g,
        (__attribute__((address_space(3))) void*)l, 16, 0, 0);
}

// ---------------------------------------------------------------------------
// ONE conversion kernel: x 3-split + 4 weights 3-split-transpose + Wo 1-plane.
// ---------------------------------------------------------------------------
__global__ __launch_bounds__(256) void conv_all(
    const float* __restrict__ x, const float* __restrict__ Wkvd,
    const float* __restrict__ Wqd, const float* __restrict__ Wkvu,
    const float* __restrict__ Wqu, const float* __restrict__ Wo,
    unsigned short* __restrict__ xh, unsigned short* __restrict__ xm,
    unsigned short* __restrict__ xl,
    unsigned short* __restrict__ Wdh, unsigned short* __restrict__ Wdm,
    unsigned short* __restrict__ Wdl,
    unsigned short* __restrict__ Wuh, unsigned short* __restrict__ Wum,
    unsigned short* __restrict__ Wul,
    unsigned short* __restrict__ Wqh, unsigned short* __restrict__ Wqm,
    unsigned short* __restrict__ Wql,
    unsigned short* __restrict__ Wo1)
{
    __shared__ float tile[32][33];
    int bid = blockIdx.x, tid = threadIdx.x;
    if (bid < 2050) {
        int i = bid * 1024 + tid * 4;
        f32x4 v = *(const f32x4*)(x + i);
#pragma unroll
        for (int j = 0; j < 4; ++j) {
            unsigned short h, m, l;
            split3(v[j], h, m, l);
            xh[i + j] = h; xm[i + j] = m; xl[i + j] = l;
        }
        return;
    }
    bid -= 2050;
    const float* W; unsigned short *Th, *Tm, *Tl; int K, N, gx;
    if (bid < 288)              { W = Wkvd; Th = Wdh; Tm = Wdm; Tl = Wdl; K = 1024; N = 288;  gx = 9;  }
    else if ((bid -= 288) < 384){ W = Wqd;  Th = Wdh + (size_t)288*1024; Tm = Wdm + (size_t)288*1024;
                                  Tl = Wdl + (size_t)288*1024; K = 1024; N = 384; gx = 12; }
    else if ((bid -= 384) < 512){ W = Wkvu; Th = Wuh; Tm = Wum; Tl = Wul; K = 256;  N = 2048; gx = 64; }
    else if ((bid -= 512) < 576){ W = Wqu;  Th = Wqh; Tm = Wqm; Tl = Wql; K = 384;  N = 1536; gx = 48; }
    else { bid -= 576;            W = Wo;   Th = Wo1; Tm = nullptr; Tl = nullptr; K = 1024; N = 1024; gx = 32; }

    int n0 = (bid % gx) * 32, k0 = (bid / gx) * 32;
    int tx = tid & 31, ty = tid >> 5;
    for (int kk = ty; kk < 32; kk += 8)
        tile[kk][tx] = W[(size_t)(k0 + kk) * N + n0 + tx];
    __syncthreads();
    for (int nn = ty; nn < 32; nn += 8) {
        int n = n0 + nn, k = k0 + tx;
        float v = tile[tx][nn];
        if (Tm) {
            unsigned short h, m, l;
            split3(v, h, m, l);
            Th[(size_t)n * K + k] = h;
            Tm[(size_t)n * K + k] = m;
            Tl[(size_t)n * K + k] = l;
        } else {
            Th[(size_t)n * K + k] = f2bf(v);
        }
    }
}

// ---------------------------------------------------------------------------
// 3-way split MFMA GEMM body, frag-ordered LDS staged via global_load_lds
// (width=16; OOB rows clamped — garbage never stored). [kb,ke) K-range.
// epi==1 writes V in TILED-TRANSPOSED layout (attention's Vt LDS layout).
// epi==2 scales Q by QSCALE (KSCALE * log2(e)) for exp2-based softmax.
// ---------------------------------------------------------------------------
__device__ __forceinline__ void gemm3_body(
    unsigned short* LA, unsigned short* LB,
    const unsigned short* __restrict__ Ah, const unsigned short* __restrict__ Am,
    const unsigned short* __restrict__ Al,
    const unsigned short* __restrict__ Bh, const unsigned short* __restrict__ Bm,
    const unsigned short* __restrict__ Bl,
    float* __restrict__ C,
    unsigned short* __restrict__ D0, unsigned short* __restrict__ D1,
    unsigned short* __restrict__ D2, unsigned short* __restrict__ D3,
    const float* __restrict__ fcos, const float* __restrict__ fsin,
    int M, int N, int K, int kb, int ke, int epi, int bm, int bn)
{
    int tid = threadIdx.x;
    int wid = tid >> 6, lane = tid & 63;
    int la = lane & 15, lb = lane >> 4;
    int wr = (wid >> 1) * 64, wc = (wid & 1) * 64;
    int wr4 = wr >> 4, wc4 = wc >> 4;

    const unsigned short* APl[3] = {Ah, Am, Al};
    const unsigned short* BPl[3] = {Bh, Bm, Bl};

    // staging coords (fixed per thread): row/kc within the 128x32 tile
    int sg = tid >> 6, spos = tid & 63;
    int rowA0 = (sg << 4) + (spos & 15);          // it = 0
    int rowA1 = ((sg + 4) << 4) + (spos & 15);    // it = 1
    int kc = (spos >> 4) * 8;
    int wb = tid & 192;                           // wave-uniform LDS chunk base

    f32x4 acc[4][4];
#pragma unroll
    for (int m = 0; m < 4; ++m)
#pragma unroll
        for (int n = 0; n < 4; ++n) acc[m][n] = (f32x4){0.f, 0.f, 0.f, 0.f};

    auto LDF = [&](bf16x8* dst, const unsigned short* Lb, int p, int rb) {
#pragma unroll
        for (int q = 0; q < 4; ++q)
            dst[q] = *(const bf16x8*)&Lb[p * 4096 + ((rb + q) * 64 + lane) * 8];
    };
    auto MM = [&](bf16x8* av, bf16x8* bv) {
#pragma unroll
        for (int m = 0; m < 4; ++m)
#pragma unroll
            for (int n = 0; n < 4; ++n)
                acc[m][n] = MFMA(av[m], bv[n], acc[m][n]);
    };

    int grA0 = bm + rowA0; if (grA0 >= M) grA0 = M - 1;
    int grA1 = bm + rowA1; if (grA1 >= M) grA1 = M - 1;
    int gnB0 = bn + rowA0; if (gnB0 >= N) gnB0 = N - 1;
    int gnB1 = bn + rowA1; if (gnB1 >= N) gnB1 = N - 1;

    for (int k0 = kb; k0 < ke; k0 += 32) {
        __syncthreads();   // previous-tile reads complete before overwrite
#pragma unroll
        for (int p = 0; p < 3; ++p) {
            gl16(APl[p] + (size_t)grA0 * K + k0 + kc, &LA[p * 4096 + wb * 8]);
            gl16(APl[p] + (size_t)grA1 * K + k0 + kc, &LA[p * 4096 + (256 + wb) * 8]);
            gl16(BPl[p] + (size_t)gnB0 * K + k0 + kc, &LB[p * 4096 + wb * 8]);
            gl16(BPl[p] + (size_t)gnB1 * K + k0 + kc, &LB[p * 4096 + (256 + wb) * 8]);
        }
        __syncthreads();   // compiler drains vmcnt before barrier
        bf16x8 av[4], bv0[4], bv1[4], bvt[4];
        LDF(av, LA, 0, wr4); LDF(bv0, LB, 0, wc4);
        LDF(bv1, LB, 1, wc4); LDF(bvt, LB, 2, wc4);
        __builtin_amdgcn_s_setprio(1);
        MM(av, bv0); MM(av, bv1); MM(av, bvt);   // hh hm hl
        __builtin_amdgcn_s_setprio(0);
        LDF(bvt, LA, 1, wr4);
        __builtin_amdgcn_s_setprio(1);
        MM(bvt, bv0); MM(bvt, bv1);              // mh mm
        __builtin_amdgcn_s_setprio(0);
        LDF(bvt, LA, 2, wr4);
        __builtin_amdgcn_s_setprio(1);
        MM(bvt, bv0);                            // lh
        __builtin_amdgcn_s_setprio(0);
    }

#pragma unroll
    for (int m = 0; m < 4; ++m)
#pragma unroll
        for (int n = 0; n < 4; ++n) {
            int gc = bn + wc + n * 16 + la;
#pragma unroll
            for (int r = 0; r < 4; ++r) {
                int gr = bm + wr + m * 16 + lb * 4 + r;
                float v = acc[m][n][r];
                if (epi == 0) {
                    if (gr < M && gc < N) C[(size_t)gr * N + gc] = v;
                } else if (epi == 1) {
                    if (gr < M) {
                        int b = gr / SEQ, s = gr - b * SEQ;
                        int h2 = gc >> 7, rem = gc & 127;
                        if (rem < 64) {
                            int H = 2 * h2 + (rem >> 5), d = rem & 31;
                            size_t idx = (((size_t)b * NH2 + H) * SEQ + s) * 48 + d;
                            unsigned short hh, mm2, ll;
                            split3(v, hh, mm2, ll);
                            D0[idx] = hh; D1[idx] = mm2; D2[idx] = ll;
                        } else {
                            // V in tiled-transposed (attention Vt) layout
                            int d = rem - 64;
                            int cv = s & 63;
                            int g = ((d >> 4) << 1) + (cv >> 5);
                            int pos = (((cv & 31) >> 3) << 4) + (d & 15);
                            D3[(((size_t)b * NHEAD + h2) * NVT + (s >> 6)) * 4096
                               + g * 512 + pos * 8 + (cv & 7)] = f2bf(v);
                        }
                    }
                } else {
                    float pv = __shfl_xor(v, 1);   // before any guard
                    if (gr < M) {
                        int b = gr / SEQ, s = gr - b * SEQ;
                        int h2 = gc / 96, rem = gc - h2 * 96;
                        int H, d; float outv;
                        if (rem < 64) {
                            H = 2 * h2 + (rem >> 5); d = rem & 31; outv = v;
                        } else {
                            int dd = rem - 64;
                            int e = dd >> 4, j = (dd & 15) >> 1;
                            H = 2 * h2 + e; d = 32 + (dd & 15);
                            if (s != 0) {
                                int p = (s - 1) & 255;
                                float cc = fcos[p * 8 + j], sn = fsin[p * 8 + j];
                                outv = ((la & 1) == 0) ? (v * cc - pv * sn)
                                                       : (pv * sn + v * cc);
                            } else outv = v;
                        }
                        outv *= QSCALE;
                        size_t idx = (((size_t)b * NH2 + H) * SEQ + s) * 48 + d;
                        unsigned short hh, mm2, ll;
                        split3(outv, hh, mm2, ll);
                        D0[idx] = hh; D1[idx] = mm2; D2[idx] = ll;
                    }
                }
            }
        }
}

// split-K x2 down-proj: z=0 -> C0 (k 0..511), z=1 -> C1 (k 512..1023)
__global__ __launch_bounds__(256) void gemm_down(
    const unsigned short* __restrict__ Ah, const unsigned short* __restrict__ Am,
    const unsigned short* __restrict__ Al,
    const unsigned short* __restrict__ Bh, const unsigned short* __restrict__ Bm,
    const unsigned short* __restrict__ Bl,
    float* __restrict__ C0, float* __restrict__ C1)
{
    __shared__ __align__(16) unsigned short LA[3 * 4096];
    __shared__ __align__(16) unsigned short LB[3 * 4096];
    int z = blockIdx.z;
    gemm3_body(LA, LB, Ah, Am, Al, Bh, Bm, Bl, z ? C1 : C0,
               nullptr, nullptr, nullptr, nullptr, nullptr, nullptr,
               R_TOT, 672, 1024, z * 512, z * 512 + 512, 0,
               blockIdx.y * 128, blockIdx.x * 128);
}

// merged kv-up (bx<16) + q-up (bx>=16)
__global__ __launch_bounds__(256) void gemm_up(
    const unsigned short* __restrict__ cnh, const unsigned short* __restrict__ cnm,
    const unsigned short* __restrict__ cnl,
    const unsigned short* __restrict__ Wuh, const unsigned short* __restrict__ Wum,
    const unsigned short* __restrict__ Wul,
    const unsigned short* __restrict__ qnh, const unsigned short* __restrict__ qnm,
    const unsigned short* __restrict__ qnl,
    const unsigned short* __restrict__ Wqh, const unsigned short* __restrict__ Wqm,
    const unsigned short* __restrict__ Wql,
    unsigned short* __restrict__ Kah, unsigned short* __restrict__ Kam,
    unsigned short* __restrict__ Kal, unsigned short* __restrict__ Va,
    unsigned short* __restrict__ Qah, unsigned short* __restrict__ Qam,
    unsigned short* __restrict__ Qal,
    const float* __restrict__ fcos, const float* __restrict__ fsin)
{
    __shared__ __align__(16) unsigned short LA[3 * 4096];
    __shared__ __align__(16) unsigned short LB[3 * 4096];
    bool isq = (blockIdx.x >= 16);
    if (!isq)
        gemm3_body(LA, LB, cnh, cnm, cnl, Wuh, Wum, Wul, nullptr,
                   Kah, Kam, Kal, Va, nullptr, nullptr,
                   R_TOT, 2048, 256, 0, 256, 1, blockIdx.y * 128, blockIdx.x * 128);
    else
        gemm3_body(LA, LB, qnh, qnm, qnl, Wqh, Wqm, Wql, nullptr,
                   Qah, Qam, Qal, nullptr, fcos, fsin,
                   R_TOT, 1536, 384, 0, 384, 2, blockIdx.y * 128, (blockIdx.x - 16) * 128);
}

// ---------------------------------------------------------------------------
// 1-plane bf16 GEMM (out-proj), frag-ordered LDS via global_load_lds.
// ---------------------------------------------------------------------------
__global__ __launch_bounds__(256) void gemm_out(
    const unsigned short* __restrict__ Ah, const unsigned short* __restrict__ Bh,
    float* __restrict__ C, int M, int N, int K)
{
    __shared__ __align__(16) unsigned short As[4096];
    __shared__ __align__(16) unsigned short Bs[4096];
    int tid = threadIdx.x;
    int wid = tid >> 6, lane = tid & 63;
    int la = lane & 15, lb = lane >> 4;
    int bm = blockIdx.y * 128, bn = blockIdx.x * 128;
    int wr = (wid >> 1) * 64, wc = (wid & 1) * 64;
    int wr4 = wr >> 4, wc4 = wc >> 4;

    int sg = tid >> 6, spos = tid & 63;
    int rowA0 = (sg << 4) + (spos & 15);
    int rowA1 = ((sg + 4) << 4) + (spos & 15);
    int kc = (spos >> 4) * 8;
    int wb = tid & 192;
    int grA0 = bm + rowA0; if (grA0 >= M) grA0 = M - 1;
    int grA1 = bm + rowA1; if (grA1 >= M) grA1 = M - 1;
    int gnB0 = bn + rowA0; if (gnB0 >= N) gnB0 = N - 1;
    int gnB1 = bn + rowA1; if (gnB1 >= N) gnB1 = N - 1;

    f32x4 acc[4][4];
#pragma unroll
    for (int m = 0; m < 4; ++m)
#pragma unroll
        for (int n = 0; n < 4; ++n) acc[m][n] = (f32x4){0.f, 0.f, 0.f, 0.f};
    for (int k0 = 0; k0 < K; k0 += 32) {
        __syncthreads();
        gl16(Ah + (size_t)grA0 * K + k0 + kc, &As[wb * 8]);
        gl16(Ah + (size_t)grA1 * K + k0 + kc, &As[(256 + wb) * 8]);
        gl16(Bh + (size_t)gnB0 * K + k0 + kc, &Bs[wb * 8]);
        gl16(Bh + (size_t)gnB1 * K + k0 + kc, &Bs[(256 + wb) * 8]);
        __syncthreads();
        bf16x8 a_[4], b_[4];
#pragma unroll
        for (int m = 0; m < 4; ++m) a_[m] = *(const bf16x8*)&As[((wr4 + m) * 64 + lane) * 8];
#pragma unroll
        for (int n = 0; n < 4; ++n) b_[n] = *(const bf16x8*)&Bs[((wc4 + n) * 64 + lane) * 8];
        __builtin_amdgcn_s_setprio(1);
#pragma unroll
        for (int m = 0; m < 4; ++m)
#pragma unroll
            for (int n = 0; n < 4; ++n) acc[m][n] = MFMA(a_[m], b_[n], acc[m][n]);
        __builtin_amdgcn_s_setprio(0);
    }
#pragma unroll
    for (int m = 0; m < 4; ++m)
#pragma unroll
        for (int n = 0; n < 4; ++n) {
            int gc = bn + wc + n * 16 + la;
            if (gc >= N) continue;
#pragma unroll
            for (int r = 0; r < 4; ++r) {
                int gr = bm + wr + m * 16 + lb * 4 + r;
                if (gr < M) C[(size_t)gr * N + gc] = acc[m][n][r];
            }
        }
}

// ---------------------------------------------------------------------------
// RMS-norm both streams (summing the two split-K partials) + K-rope 3-plane.
// ---------------------------------------------------------------------------
__global__ __launch_bounds__(256) void k_rmsrope3(
    const float* __restrict__ ckvqd, const float* __restrict__ ckvqd2,
    unsigned short* __restrict__ cnh, unsigned short* __restrict__ cnm,
    unsigned short* __restrict__ cnl,
    unsigned short* __restrict__ qnh, unsigned short* __restrict__ qnm,
    unsigned short* __restrict__ qnl,
    unsigned short* __restrict__ Kah, unsigned short* __restrict__ Kam,
    unsigned short* __restrict__ Kal,
    const float* __restrict__ gkv, const float* __restrict__ gq,
    const float* __restrict__ fcos, const float* __restrict__ fsin)
{
    __shared__ float red[256];
    __shared__ float rot[32];
    int row = blockIdx.x, tid = threadIdx.x;
    int b = row / SEQ, s = row - b * SEQ;
    const float* cp  = ckvqd  + (size_t)row * 672;
    const float* cp2 = ckvqd2 + (size_t)row * 672;
    float c0 = cp[tid] + cp2[tid];
    float q0 = cp[288 + tid] + cp2[288 + tid];
    float q1 = (tid < 128) ? (cp[544 + tid] + cp2[544 + tid]) : 0.f;

    red[tid] = c0 * c0;
    __syncthreads();
    for (int o = 128; o; o >>= 1) { if (tid < o) red[tid] += red[tid + o]; __syncthreads(); }
    float inv1 = rsqrtf(red[0] * (1.f / 256.f) + EPS_RMS);
    __syncthreads();
    red[tid] = q0 * q0 + q1 * q1;
    __syncthreads();
    for (int o = 128; o; o >>= 1) { if (tid < o) red[tid] += red[tid + o]; __syncthreads(); }
    float inv2 = rsqrtf(red[0] * (1.f / 384.f) + EPS_RMS);

    unsigned short h, m, l;
    split3(c0 * inv1 * gkv[tid], h, m, l);
    size_t ci = (size_t)row * 256 + tid;
    cnh[ci] = h; cnm[ci] = m; cnl[ci] = l;

    split3(q0 * inv2 * gq[tid], h, m, l);
    size_t qi = (size_t)row * 384 + tid;
    qnh[qi] = h; qnm[qi] = m; qnl[qi] = l;
    if (tid < 128) {
        split3(q1 * inv2 * gq[256 + tid], h, m, l);
        qnh[qi + 256] = h; qnm[qi + 256] = m; qnl[qi + 256] = l;
    }

    if (tid < 16) {
        float r0 = cp[256 + 2 * tid] + cp2[256 + 2 * tid];
        float r1 = cp[256 + 2 * tid + 1] + cp2[256 + 2 * tid + 1];
        float o0, o1;
        if (s == 0) { o0 = r0; o1 = r1; }
        else {
            int p = (s - 1) & 255;
            int j = tid & 7;
            float cc = fcos[p * 8 + j], sn = fsin[p * 8 + j];
            o0 = r0 * cc - r1 * sn;
            o1 = r0 * sn + r1 * cc;
        }
        rot[2 * tid] = o0; rot[2 * tid + 1] = o1;
    }
    __syncthreads();
    for (int t = tid; t < 512; t += 256) {
        int H = t >> 4, dd = t & 15;
        int e = H & 1;
        split3(rot[e * 16 + dd], h, m, l);
        size_t idx = (((size_t)b * NH2 + H) * SEQ + s) * 48 + 32 + dd;
        Kah[idx] = h; Kam[idx] = m; Kal[idx] = l;
    }
}

// ---------------------------------------------------------------------------
// MFMA cog-attention v13 = v12 + Pl XOR swizzle (block P = L ^ ((L>>3)&3);
// XOR is a per-thread constant for both writes and reads -> 8-way P-write
// bank conflicts -> 2-way/free, reads stay conflict-free b128) + exp2-based
// softmax (log2e folded into QSCALE upstream). Pipeline/math unchanged.
// ---------------------------------------------------------------------------
__global__ __launch_bounds__(256, 2) void k_attn13(
    const unsigned short* __restrict__ Qah, const unsigned short* __restrict__ Qam,
    const unsigned short* __restrict__ Qal,
    const unsigned short* __restrict__ Kah, const unsigned short* __restrict__ Kam,
    const unsigned short* __restrict__ Kal,
    const unsigned short* __restrict__ Va, const float* __restrict__ ghead,
    const float* __restrict__ lq1, const float* __restrict__ lk1,
    const float* __restrict__ lq2, const float* __restrict__ lk2,
    unsigned short* __restrict__ attO)
{
    __shared__ __align__(16) unsigned short KS[6][3072];
    __shared__ __align__(16) unsigned short Vt[4096];
    __shared__ __align__(16) unsigned short Pl[4][1024];

    int bid0 = blockIdx.x;
    int bid = (bid0 & 7) * 68 + (bid0 >> 3);   // bijective XCD swizzle (544=8*68)
    int rt = bid % 17;
    int bh = bid / 17;
    int h = bh & 15, b = bh >> 4;
    int tid = threadIdx.x, wid = tid >> 6, lane = tid & 63;
    int la = lane & 15, lb = lane >> 4;
    int r0 = rt * 64, r0w = r0 + wid * 16;

    // Pl swizzle constants: P_block = L ^ ((L>>3)&3)
    int pswz = ((((la >> 3) << 1) | (lb >> 1)) << 3);   // write XOR (u16 units)
    int prd = (lane * 8) ^ (((lane >> 3) & 3) << 3);    // read offset (both halves)

    float e1 = 0.f, e2 = 0.f;
    for (int i = 0; i < 32; ++i) { e1 = fmaf(lq1[i], lk1[i], e1); e2 = fmaf(lq2[i], lk2[i], e2); }
    float lam = __expf(e1) - __expf(e2) + LAMBDA_INIT;

    int pr[4];
#pragma unroll
    for (int g = 0; g < 4; ++g) {
        int r = r0w + lb * 4 + g;
        pr[g] = (r >= 1 && r < SEQ) ? ((r - 1) & 255) : -1;
    }
    int rA = r0w + la;
    int prA = (rA >= 1 && rA < SEQ) ? ((rA - 1) & 255) : -1;

    int prm = -1;
    for (int i = 0; i < 64; ++i) {
        int r = r0 + i;
        if (r >= 1 && r < SEQ) { int p = (r - 1) & 255; prm = p > prm ? p : prm; }
    }

    const size_t hb1 = ((size_t)(b * NH2 + 2 * h)) * SEQ * 48;
    const size_t hb2 = ((size_t)(b * NH2 + 2 * h + 1)) * SEQ * 48;
    const unsigned short* vg = Va + ((size_t)(b * NHEAD + h)) * NVT * 4096;
    const unsigned short* KP[6] = {Kah + hb1, Kam + hb1, Kal + hb1,
                                   Kah + hb2, Kam + hb2, Kal + hb2};

    int qrow = r0w + la; if (qrow > SEQ - 1) qrow = SEQ - 1;
    bf16x8 zf;
#pragma unroll
    for (int u = 0; u < 8; ++u) zf[u] = 0;
    bf16x8 q1[3][2], q2[3][2];
    {
        const unsigned short* QPl[3] = {Qah, Qam, Qal};
#pragma unroll
        for (int p = 0; p < 3; ++p)
#pragma unroll
            for (int f = 0; f < 2; ++f) {
                if (f == 0 || lb < 2) {
                    q1[p][f] = *(const bf16x8*)(QPl[p] + hb1 + (size_t)qrow * 48 + 32 * f + lb * 8);
                    q2[p][f] = *(const bf16x8*)(QPl[p] + hb2 + (size_t)qrow * 48 + 32 * f + lb * 8);
                } else { q1[p][f] = zf; q2[p][f] = zf; }
            }
    }

    // K staging chunk map: ci -> (col, k-octet u)
    int colA, uA, colB = 0, uB = 0;
    {
        int ci = tid;
        colA = ((ci >> 6) << 4) + (ci & 15);
        uA = (ci >> 4) & 3;
        if (tid < 128) {
            int c2 = tid;
            colB = ((c2 >> 5) << 4) + (c2 & 15);
            uB = 4 + ((c2 >> 4) & 1);
        }
    }

    i32x4 preA[6], preB[6], vv[2];
    auto LOADT = [&](int c0n) {
        int gcA = c0n + colA; if (gcA > SEQ - 1) gcA = SEQ - 1;
#pragma unroll
        for (int p = 0; p < 6; ++p)
            preA[p] = *(const i32x4*)(KP[p] + (size_t)gcA * 48 + uA * 8);
        if (tid < 128) {
            int gcB = c0n + colB; if (gcB > SEQ - 1) gcB = SEQ - 1;
#pragma unroll
            for (int p = 0; p < 6; ++p)
                preB[p] = *(const i32x4*)(KP[p] + (size_t)gcB * 48 + uB * 8);
        }
        const unsigned short* vt = vg + (size_t)(c0n >> 6) * 4096;
        vv[0] = *(const i32x4*)(vt + tid * 8);
        vv[1] = *(const i32x4*)(vt + 2048 + tid * 8);
    };
    auto WRITET = [&]() {
#pragma unroll
        for (int p = 0; p < 6; ++p)
            *(i32x4*)&KS[p][tid * 8] = preA[p];          // linear, conflict-free
        if (tid < 128) {
#pragma unroll
            for (int p = 0; p < 6; ++p)
                *(i32x4*)&KS[p][2048 + tid * 8] = preB[p];
        }
        *(i32x4*)&Vt[tid * 8] = vv[0];                   // linear, conflict-free
        *(i32x4*)&Vt[2048 + tid * 8] = vv[1];
    };

    f32x4 O1[4], O2[4], VS[4];
#pragma unroll
    for (int nd = 0; nd < 4; ++nd) {
        O1[nd] = (f32x4){0.f, 0.f, 0.f, 0.f};
        O2[nd] = (f32x4){0.f, 0.f, 0.f, 0.f};
        VS[nd] = (f32x4){0.f, 0.f, 0.f, 0.f};
    }
    float dA1[4] = {0.f, 0.f, 0.f, 0.f}, dA2[4] = {0.f, 0.f, 0.f, 0.f};
    float gsA[4] = {0.f, 0.f, 0.f, 0.f};
    f32x4 z = (f32x4){0.f, 0.f, 0.f, 0.f};

    LOADT(0);
    WRITET();
    __syncthreads();

    for (int j = 0; j <= 16; ++j) {
        bool need = (j == 16) ? (prm >= 255)
                              : (((j & 3) == 0) || (prm >= 64 * (j & 3) - 1));
        if (!need) continue;
        int c0 = j * 64;

        int nj = -1;
        for (int t2 = j + 1; t2 <= 16; ++t2) {
            bool nd2 = (t2 == 16) ? (prm >= 255)
                                  : (((t2 & 3) == 0) || (prm >= 64 * (t2 & 3) - 1));
            if (nd2) { nj = t2; break; }
        }
        if (nj >= 0) LOADT(nj * 64);

        // ---- scores S1 / S2 (packed-layout frag reads) ----
        f32x4 s1[4], s2[4];
        __builtin_amdgcn_s_setprio(1);
#pragma unroll
        for (int n = 0; n < 4; ++n) {
            int g0 = n * 512 + lane * 8;
            int g1 = 2048 + n * 256 + (lane & 31) * 8;
            bf16x8 kh0 = *(const bf16x8*)&KS[0][g0];
            bf16x8 kh1 = *(const bf16x8*)&KS[0][g1];
            bf16x8 km0 = *(const bf16x8*)&KS[1][g0];
            bf16x8 km1 = *(const bf16x8*)&KS[1][g1];
            bf16x8 kl0 = *(const bf16x8*)&KS[2][g0];
            bf16x8 kl1 = *(const bf16x8*)&KS[2][g1];
            f32x4 s = z;
            s = MFMA(q1[0][0], kh0, s); s = MFMA(q1[0][1], kh1, s);
            s = MFMA(q1[0][0], km0, s); s = MFMA(q1[0][1], km1, s);
            s = MFMA(q1[1][0], kh0, s); s = MFMA(q1[1][1], kh1, s);
            s = MFMA(q1[0][0], kl0, s); s = MFMA(q1[0][1], kl1, s);
            s = MFMA(q1[1][0], km0, s); s = MFMA(q1[1][1], km1, s);
            s = MFMA(q1[2][0], kh0, s); s = MFMA(q1[2][1], kh1, s);
            s1[n] = s;
        }
#pragma unroll
        for (int n = 0; n < 4; ++n) {
            int g0 = n * 512 + lane * 8;
            int g1 = 2048 + n * 256 + (lane & 31) * 8;
            bf16x8 kh0 = *(const bf16x8*)&KS[3][g0];
            bf16x8 kh1 = *(const bf16x8*)&KS[3][g1];
            bf16x8 km0 = *(const bf16x8*)&KS[4][g0];
            bf16x8 km1 = *(const bf16x8*)&KS[4][g1];
            bf16x8 kl0 = *(const bf16x8*)&KS[5][g0];
            bf16x8 kl1 = *(const bf16x8*)&KS[5][g1];
            f32x4 s = z;
            s = MFMA(q2[0][0], kh0, s); s = MFMA(q2[0][1], kh1, s);
            s = MFMA(q2[0][0], km0, s); s = MFMA(q2[0][1], km1, s);
            s = MFMA(q2[1][0], kh0, s); s = MFMA(q2[1][1], kh1, s);
            s = MFMA(q2[0][0], kl0, s); s = MFMA(q2[0][1], kl1, s);
            s = MFMA(q2[1][0], km0, s); s = MFMA(q2[1][1], km1, s);
            s = MFMA(q2[2][0], kh0, s); s = MFMA(q2[2][1], kh1, s);
            s2[n] = s;
        }
        __builtin_amdgcn_s_setprio(0);

        // ---- slim no-max signed softmax (exp2; log2e pre-folded into Q) ----
        unsigned short p1v[4][4], p2v[4][4];
#pragma unroll
        for (int n = 0; n < 4; ++n) {
            int c = c0 + n * 16 + la;
            bool cz = (c == 0);
            int cm = (c - 1) & 255;
            bool cin = (c < SEQ);
#pragma unroll
            for (int g = 0; g < 4; ++g) {
                bool al = cz || (cin && cm <= pr[g]);
                float a = s1[n][g];
                float sa = __builtin_copysignf(__builtin_amdgcn_exp2f(fabsf(a)), a);
                sa = al ? sa : 0.f;
                p1v[n][g] = (unsigned short)((__float_as_uint(sa) + 0x8000u) >> 16);
                gsA[g] += sa;
                dA1[g] += fabsf(sa);
                float bb = s2[n][g];
                float sb = __builtin_copysignf(__builtin_amdgcn_exp2f(fabsf(bb)), bb);
                sb = al ? sb : 0.f;
                p2v[n][g] = (unsigned short)((__float_as_uint(sb) + 0x8000u) >> 16);
                dA2[g] += fabsf(sb);
            }
        }

        // ---- P1 -> A-frags via wave-private swizzled LDS ----
#pragma unroll
        for (int n = 0; n < 4; ++n) {
            int pb = (n >> 1) * 512 + (((n & 1) << 1) + (la >> 3)) * 128 + (la & 7);
#pragma unroll
            for (int g = 0; g < 4; ++g)
                Pl[wid][(pb + (lb * 4 + g) * 8) ^ pswz] = p1v[n][g];
        }
        __asm__ volatile("s_waitcnt lgkmcnt(0)" ::: "memory");
        __builtin_amdgcn_sched_barrier(0);
        bf16x8 p1a0 = *(const bf16x8*)&Pl[wid][prd];
        bf16x8 p1a1 = *(const bf16x8*)&Pl[wid][512 + prd];
#pragma unroll
        for (int n = 0; n < 4; ++n) {
            int pb = (n >> 1) * 512 + (((n & 1) << 1) + (la >> 3)) * 128 + (la & 7);
#pragma unroll
            for (int g = 0; g < 4; ++g)
                Pl[wid][(pb + (lb * 4 + g) * 8) ^ pswz] = p2v[n][g];
        }
        __asm__ volatile("s_waitcnt lgkmcnt(0)" ::: "memory");
        __builtin_amdgcn_sched_barrier(0);
        bf16x8 p2a0 = *(const bf16x8*)&Pl[wid][prd];
        bf16x8 p2a1 = *(const bf16x8*)&Pl[wid][512 + prd];

        // mask-frags for Vsum
        bf16x8 p0[2];
#pragma unroll
        for (int f = 0; f < 2; ++f)
#pragma unroll
            for (int jb = 0; jb < 8; ++jb) {
                int c = c0 + 32 * f + lb * 8 + jb;
                bool al = (c == 0) || (c < SEQ && ((c - 1) & 255) <= prA);
                p0[f][jb] = al ? (short)0x3F80 : (short)0;
            }

        // ---- PV + VS ----
        __builtin_amdgcn_s_setprio(1);
#pragma unroll
        for (int nd = 0; nd < 4; ++nd) {
            bf16x8 vb0 = *(const bf16x8*)&Vt[(nd * 2) * 512 + lane * 8];
            bf16x8 vb1 = *(const bf16x8*)&Vt[(nd * 2 + 1) * 512 + lane * 8];
            O1[nd] = MFMA(p1a0, vb0, O1[nd]);
            O1[nd] = MFMA(p1a1, vb1, O1[nd]);
            O2[nd] = MFMA(p2a0, vb0, O2[nd]);
            O2[nd] = MFMA(p2a1, vb1, O2[nd]);
            VS[nd] = MFMA(p0[0], vb0, VS[nd]);
            VS[nd] = MFMA(p0[1], vb1, VS[nd]);
        }
        __builtin_amdgcn_s_setprio(0);

        if (nj >= 0) {
            __syncthreads();
            WRITET();
            __syncthreads();
        }
    }

    // ---- final reductions ----
#pragma unroll
    for (int off = 1; off < 16; off <<= 1) {
#pragma unroll
        for (int g = 0; g < 4; ++g) {
            dA1[g] += __shfl_xor(dA1[g], off);
            dA2[g] += __shfl_xor(dA2[g], off);
            gsA[g] += __shfl_xor(gsA[g], off);
        }
    }

    float i1[4], i2g[4], Gl[4];
#pragma unroll
    for (int g = 0; g < 4; ++g) {
        i1[g] = 1.f / dA1[g];
        i2g[g] = 1.f / dA2[g];
        Gl[g] = gsA[g] * i1[g] * (1.f / (float)SEQ) * lam;
    }
    f32x4 outv[4];
#pragma unroll
    for (int nd = 0; nd < 4; ++nd)
#pragma unroll
        for (int g = 0; g < 4; ++g)
            outv[nd][g] = O1[nd][g] * i1[g] - lam * i2g[g] * O2[nd][g] + Gl[g] * VS[nd][g];

    float ssq[4] = {0.f, 0.f, 0.f, 0.f};
#pragma unroll
    for (int nd = 0; nd < 4; ++nd)
#pragma unroll
        for (int g = 0; g < 4; ++g) ssq[g] += outv[nd][g] * outv[nd][g];
#pragma unroll
    for (int off = 1; off < 16; off <<= 1)
#pragma unroll
        for (int g = 0; g < 4; ++g) ssq[g] += __shfl_xor(ssq[g], off);
    float inv[4];
#pragma unroll
    for (int g = 0; g < 4; ++g) inv[g] = rsqrtf(ssq[g] * (1.f / 64.f) + EPS_HEAD);

#pragma unroll
    for (int nd = 0; nd < 4; ++nd) {
        int d = nd * 16 + la;
        float gv = ghead[d];
#pragma unroll
        for (int g = 0; g < 4; ++g) {
            int r = r0w + lb * 4 + g;
            if (r < SEQ)
                attO[(((size_t)b * SEQ + r) * NHEAD + h) * 64 + d] =
                    f2bf(outv[nd][g] * inv[g] * gv);
        }
    }
}

// ---------------------------------------------------------------------------
extern "C" void kernel_launch(void* const* d_in, const int* in_sizes, int n_in,
                              void* d_out, int out_size, void* d_ws, size_t ws_size,
                              hipStream_t stream)
{
    const float* x    = (const float*)d_in[0];
    const float* fcos = (const float*)d_in[2];
    const float* fsin = (const float*)d_in[3];
    const float* Wkvd = (const float*)d_in[4];
    const float* Wqd  = (const float*)d_in[5];
    const float* Wkvu = (const float*)d_in[6];
    const float* Wqu  = (const float*)d_in[7];
    const float* Wo   = (const float*)d_in[8];
    const float* gkv  = (const float*)d_in[9];
    const float* gq   = (const float*)d_in[10];
    const float* gh   = (const float*)d_in[11];
    const float* lq1  = (const float*)d_in[12];
    const float* lk1  = (const float*)d_in[13];
    const float* lq2  = (const float*)d_in[14];
    const float* lk2  = (const float*)d_in[15];
    float* out = (float*)d_out;

    const int R = R_TOT;  // 2050
    char* base = (char*)d_ws;
    size_t off = 0;
    auto alloc = [&](size_t bytes) -> char* {
        char* p = base + off;
        off = (off + bytes + 255) & ~(size_t)255;
        return p;
    };
    const size_t KPL = (size_t)BATCH * NH2 * SEQ * 48 * 2;   // per K/Q plane
    const size_t VAB = (size_t)BATCH * NHEAD * NVT * 4096 * 2;  // tiled Vt

    unsigned short* xh = (unsigned short*)alloc((size_t)R * 1024 * 2);
    unsigned short* xm = (unsigned short*)alloc((size_t)R * 1024 * 2);
    unsigned short* xl = (unsigned short*)alloc((size_t)R * 1024 * 2);
    unsigned short* attO = xh;                      // x dead after down-GEMM
    unsigned short* Kah  = xm;                      // KPL fits xm+xl

    float* ckvqd = (float*)alloc((size_t)R * 672 * 4);
    unsigned short* cnh = (unsigned short*)alloc((size_t)R * 256 * 2);
    unsigned short* cnm = (unsigned short*)alloc((size_t)R * 256 * 2);
    unsigned short* cnl = (unsigned short*)alloc((size_t)R * 256 * 2);
    unsigned short* qnh = (unsigned short*)alloc((size_t)R * 384 * 2);
    unsigned short* qnm = (unsigned short*)alloc((size_t)R * 384 * 2);
    unsigned short* qnl = (unsigned short*)alloc((size_t)R * 384 * 2);
    unsigned short* Kam = (unsigned short*)alloc(KPL);
    unsigned short* Kal = (unsigned short*)alloc(KPL);
    unsigned short* Qah = (unsigned short*)alloc(KPL);
    unsigned short* Qam = (unsigned short*)alloc(KPL);
    unsigned short* Qal = (unsigned short*)alloc(KPL);
    unsigned short* Va  = (unsigned short*)alloc(VAB);
    unsigned short* Wdh = (unsigned short*)alloc((size_t)672 * 1024 * 2);
    unsigned short* Wdm = (unsigned short*)alloc((size_t)672 * 1024 * 2);
    unsigned short* Wdl = (unsigned short*)alloc((size_t)672 * 1024 * 2);
    unsigned short* Wuh = (unsigned short*)alloc((size_t)2048 * 256 * 2);
    unsigned short* Wum = (unsigned short*)alloc((size_t)2048 * 256 * 2);
    unsigned short* Wul = (unsigned short*)alloc((size_t)2048 * 256 * 2);
    unsigned short* Wqh = (unsigned short*)alloc((size_t)1536 * 384 * 2);
    unsigned short* Wqm = (unsigned short*)alloc((size_t)1536 * 384 * 2);
    unsigned short* Wql = (unsigned short*)alloc((size_t)1536 * 384 * 2);
    unsigned short* Wo1 = (unsigned short*)alloc((size_t)1024 * 1024 * 2);

    // split-K partial #2 for down-proj: aliases Qah (dead until gemm_up).
    float* ckvqd2 = (float*)Qah;

    dim3 blk(256);
    conv_all<<<4834, blk, 0, stream>>>(x, Wkvd, Wqd, Wkvu, Wqu, Wo,
        xh, xm, xl, Wdh, Wdm, Wdl, Wuh, Wum, Wul, Wqh, Wqm, Wql, Wo1);
    gemm_down<<<dim3(6, 17, 2), blk, 0, stream>>>(xh, xm, xl, Wdh, Wdm, Wdl,
                                                  ckvqd, ckvqd2);
    k_rmsrope3<<<R, blk, 0, stream>>>(ckvqd, ckvqd2, cnh, cnm, cnl, qnh, qnm, qnl,
                                      Kah, Kam, Kal, gkv, gq, fcos, fsin);
    // zero Va so tile-16 padding cols (>=SEQ) are 0 (they multiply P=0 anyway)
    hipMemsetAsync(Va, 0, VAB, stream);
    gemm_up<<<dim3(28, 17), blk, 0, stream>>>(cnh, cnm, cnl, Wuh, Wum, Wul,
        qnh, qnm, qnl, Wqh, Wqm, Wql, Kah, Kam, Kal, Va, Qah, Qam, Qal, fcos, fsin);
    k_attn13<<<544, blk, 0, stream>>>(Qah, Qam, Qal, Kah, Kam, Kal,
        Va, gh, lq1, lk1, lq2, lk2, attO);
    gemm_out<<<dim3(8, 17), blk, 0, stream>>>(attO, Wo1, out, R, 1024, 1024);
}

// Round 19
// 267.471 us; speedup vs baseline: 1.0408x; 1.0408x over previous
//
#include <hip/hip_runtime.h>
#include <hip/hip_bf16.h>
#include <math.h>

#define NHEAD 16
#define SEQ 1025
#define BATCH 2
#define NH2 32
#define KSCALE (1.0f/48.0f)
#define QSCALE (KSCALE * 1.4426950408889634f)   // fold log2(e): exp(|S|)=exp2(|S'|)
#define EPS_RMS 1.1920929e-07f
#define EPS_HEAD 1e-05f
#define LAMBDA_INIT 0.2f
#define R_TOT (BATCH*SEQ)
#define NVT 17              // V tiles per head (ceil(SEQ/64))

typedef __attribute__((ext_vector_type(8))) short bf16x8;
typedef __attribute__((ext_vector_type(4))) float f32x4;
typedef __attribute__((ext_vector_type(4))) int  i32x4;

static __device__ __forceinline__ unsigned short f2bf(float x) {
    unsigned int u = __float_as_uint(x);
    unsigned int r = (u + 0x7fffu + ((u >> 16) & 1u)) >> 16;
    return (unsigned short)r;
}
static __device__ __forceinline__ float bf2f(unsigned short h) {
    return __uint_as_float(((unsigned int)h) << 16);
}
static __device__ __forceinline__ void split3(float v, unsigned short& h,
                                              unsigned short& m, unsigned short& l) {
    h = f2bf(v); float r1 = v - bf2f(h);
    m = f2bf(r1); float r2 = r1 - bf2f(m);
    l = f2bf(r2);
}
static __device__ __forceinline__ f32x4 MFMA(bf16x8 a, bf16x8 b, f32x4 c) {
    return __builtin_amdgcn_mfma_f32_16x16x32_bf16(a, b, c, 0, 0, 0);
}
// async global->LDS, 16B per lane; LDS dest = wave-uniform base + lane*16
static __device__ __forceinline__ void gl16(const unsigned short* g,
                                            unsigned short* l) {
    __builtin_amdgcn_global_load_lds(
        (const __attribute__((address_space(1))) void*)g,
        (__attribute__((address_space(3))) void*)l, 16, 0, 0);
}

// ---------------------------------------------------------------------------
// ONE conversion kernel: x 3-split + 4 weights 3-split-transpose + Wo 1-plane.
// ---------------------------------------------------------------------------
__global__ __launch_bounds__(256) void conv_all(
    const float* __restrict__ x, const float* __restrict__ Wkvd,
    const float* __restrict__ Wqd, const float* __restrict__ Wkvu,
    const float* __restrict__ Wqu, const float* __restrict__ Wo,
    unsigned short* __restrict__ xh, unsigned short* __restrict__ xm,
    unsigned short* __restrict__ xl,
    unsigned short* __restrict__ Wdh, unsigned short* __restrict__ Wdm,
    unsigned short* __restrict__ Wdl,
    unsigned short* __restrict__ Wuh, unsigned short* __restrict__ Wum,
    unsigned short* __restrict__ Wul,
    unsigned short* __restrict__ Wqh, unsigned short* __restrict__ Wqm,
    unsigned short* __restrict__ Wql,
    unsigned short* __restrict__ Wo1)
{
    __shared__ float tile[32][33];
    int bid = blockIdx.x, tid = threadIdx.x;
    if (bid < 2050) {
        int i = bid * 1024 + tid * 4;
        f32x4 v = *(const f32x4*)(x + i);
#pragma unroll
        for (int j = 0; j < 4; ++j) {
            unsigned short h, m, l;
            split3(v[j], h, m, l);
            xh[i + j] = h; xm[i + j] = m; xl[i + j] = l;
        }
        return;
    }
    bid -= 2050;
    const float* W; unsigned short *Th, *Tm, *Tl; int K, N, gx;
    if (bid < 288)              { W = Wkvd; Th = Wdh; Tm = Wdm; Tl = Wdl; K = 1024; N = 288;  gx = 9;  }
    else if ((bid -= 288) < 384){ W = Wqd;  Th = Wdh + (size_t)288*1024; Tm = Wdm + (size_t)288*1024;
                                  Tl = Wdl + (size_t)288*1024; K = 1024; N = 384; gx = 12; }
    else if ((bid -= 384) < 512){ W = Wkvu; Th = Wuh; Tm = Wum; Tl = Wul; K = 256;  N = 2048; gx = 64; }
    else if ((bid -= 512) < 576){ W = Wqu;  Th = Wqh; Tm = Wqm; Tl = Wql; K = 384;  N = 1536; gx = 48; }
    else { bid -= 576;            W = Wo;   Th = Wo1; Tm = nullptr; Tl = nullptr; K = 1024; N = 1024; gx = 32; }

    int n0 = (bid % gx) * 32, k0 = (bid / gx) * 32;
    int tx = tid & 31, ty = tid >> 5;
    for (int kk = ty; kk < 32; kk += 8)
        tile[kk][tx] = W[(size_t)(k0 + kk) * N + n0 + tx];
    __syncthreads();
    for (int nn = ty; nn < 32; nn += 8) {
        int n = n0 + nn, k = k0 + tx;
        float v = tile[tx][nn];
        if (Tm) {
            unsigned short h, m, l;
            split3(v, h, m, l);
            Th[(size_t)n * K + k] = h;
            Tm[(size_t)n * K + k] = m;
            Tl[(size_t)n * K + k] = l;
        } else {
            Th[(size_t)n * K + k] = f2bf(v);
        }
    }
}

// ---------------------------------------------------------------------------
// 3-way split MFMA GEMM body, frag-ordered LDS staged via global_load_lds
// (width=16; OOB rows clamped — garbage never stored). [kb,ke) K-range.
// epi==1 writes V in TILED-TRANSPOSED layout (attention's Vt LDS layout).
// epi==2 scales Q by QSCALE (KSCALE * log2(e)) for exp2-based softmax.
// ---------------------------------------------------------------------------
__device__ __forceinline__ void gemm3_body(
    unsigned short* LA, unsigned short* LB,
    const unsigned short* __restrict__ Ah, const unsigned short* __restrict__ Am,
    const unsigned short* __restrict__ Al,
    const unsigned short* __restrict__ Bh, const unsigned short* __restrict__ Bm,
    const unsigned short* __restrict__ Bl,
    float* __restrict__ C,
    unsigned short* __restrict__ D0, unsigned short* __restrict__ D1,
    unsigned short* __restrict__ D2, unsigned short* __restrict__ D3,
    const float* __restrict__ fcos, const float* __restrict__ fsin,
    int M, int N, int K, int kb, int ke, int epi, int bm, int bn)
{
    int tid = threadIdx.x;
    int wid = tid >> 6, lane = tid & 63;
    int la = lane & 15, lb = lane >> 4;
    int wr = (wid >> 1) * 64, wc = (wid & 1) * 64;
    int wr4 = wr >> 4, wc4 = wc >> 4;

    const unsigned short* APl[3] = {Ah, Am, Al};
    const unsigned short* BPl[3] = {Bh, Bm, Bl};

    // staging coords (fixed per thread): row/kc within the 128x32 tile
    int sg = tid >> 6, spos = tid & 63;
    int rowA0 = (sg << 4) + (spos & 15);          // it = 0
    int rowA1 = ((sg + 4) << 4) + (spos & 15);    // it = 1
    int kc = (spos >> 4) * 8;
    int wb = tid & 192;                           // wave-uniform LDS chunk base

    f32x4 acc[4][4];
#pragma unroll
    for (int m = 0; m < 4; ++m)
#pragma unroll
        for (int n = 0; n < 4; ++n) acc[m][n] = (f32x4){0.f, 0.f, 0.f, 0.f};

    auto LDF = [&](bf16x8* dst, const unsigned short* Lb, int p, int rb) {
#pragma unroll
        for (int q = 0; q < 4; ++q)
            dst[q] = *(const bf16x8*)&Lb[p * 4096 + ((rb + q) * 64 + lane) * 8];
    };
    auto MM = [&](bf16x8* av, bf16x8* bv) {
#pragma unroll
        for (int m = 0; m < 4; ++m)
#pragma unroll
            for (int n = 0; n < 4; ++n)
                acc[m][n] = MFMA(av[m], bv[n], acc[m][n]);
    };

    int grA0 = bm + rowA0; if (grA0 >= M) grA0 = M - 1;
    int grA1 = bm + rowA1; if (grA1 >= M) grA1 = M - 1;
    int gnB0 = bn + rowA0; if (gnB0 >= N) gnB0 = N - 1;
    int gnB1 = bn + rowA1; if (gnB1 >= N) gnB1 = N - 1;

    for (int k0 = kb; k0 < ke; k0 += 32) {
        __syncthreads();   // previous-tile reads complete before overwrite
#pragma unroll
        for (int p = 0; p < 3; ++p) {
            gl16(APl[p] + (size_t)grA0 * K + k0 + kc, &LA[p * 4096 + wb * 8]);
            gl16(APl[p] + (size_t)grA1 * K + k0 + kc, &LA[p * 4096 + (256 + wb) * 8]);
            gl16(BPl[p] + (size_t)gnB0 * K + k0 + kc, &LB[p * 4096 + wb * 8]);
            gl16(BPl[p] + (size_t)gnB1 * K + k0 + kc, &LB[p * 4096 + (256 + wb) * 8]);
        }
        __syncthreads();   // compiler drains vmcnt before barrier
        bf16x8 av[4], bv0[4], bv1[4], bvt[4];
        LDF(av, LA, 0, wr4); LDF(bv0, LB, 0, wc4);
        LDF(bv1, LB, 1, wc4); LDF(bvt, LB, 2, wc4);
        __builtin_amdgcn_s_setprio(1);
        MM(av, bv0); MM(av, bv1); MM(av, bvt);   // hh hm hl
        __builtin_amdgcn_s_setprio(0);
        LDF(bvt, LA, 1, wr4);
        __builtin_amdgcn_s_setprio(1);
        MM(bvt, bv0); MM(bvt, bv1);              // mh mm
        __builtin_amdgcn_s_setprio(0);
        LDF(bvt, LA, 2, wr4);
        __builtin_amdgcn_s_setprio(1);
        MM(bvt, bv0);                            // lh
        __builtin_amdgcn_s_setprio(0);
    }

#pragma unroll
    for (int m = 0; m < 4; ++m)
#pragma unroll
        for (int n = 0; n < 4; ++n) {
            int gc = bn + wc + n * 16 + la;
#pragma unroll
            for (int r = 0; r < 4; ++r) {
                int gr = bm + wr + m * 16 + lb * 4 + r;
                float v = acc[m][n][r];
                if (epi == 0) {
                    if (gr < M && gc < N) C[(size_t)gr * N + gc] = v;
                } else if (epi == 1) {
                    if (gr < M) {
                        int b = gr / SEQ, s = gr - b * SEQ;
                        int h2 = gc >> 7, rem = gc & 127;
                        if (rem < 64) {
                            int H = 2 * h2 + (rem >> 5), d = rem & 31;
                            size_t idx = (((size_t)b * NH2 + H) * SEQ + s) * 48 + d;
                            unsigned short hh, mm2, ll;
                            split3(v, hh, mm2, ll);
                            D0[idx] = hh; D1[idx] = mm2; D2[idx] = ll;
                        } else {
                            // V in tiled-transposed (attention Vt) layout
                            int d = rem - 64;
                            int cv = s & 63;
                            int g = ((d >> 4) << 1) + (cv >> 5);
                            int pos = (((cv & 31) >> 3) << 4) + (d & 15);
                            D3[(((size_t)b * NHEAD + h2) * NVT + (s >> 6)) * 4096
                               + g * 512 + pos * 8 + (cv & 7)] = f2bf(v);
                        }
                    }
                } else {
                    float pv = __shfl_xor(v, 1);   // before any guard
                    if (gr < M) {
                        int b = gr / SEQ, s = gr - b * SEQ;
                        int h2 = gc / 96, rem = gc - h2 * 96;
                        int H, d; float outv;
                        if (rem < 64) {
                            H = 2 * h2 + (rem >> 5); d = rem & 31; outv = v;
                        } else {
                            int dd = rem - 64;
                            int e = dd >> 4, j = (dd & 15) >> 1;
                            H = 2 * h2 + e; d = 32 + (dd & 15);
                            if (s != 0) {
                                int p = (s - 1) & 255;
                                float cc = fcos[p * 8 + j], sn = fsin[p * 8 + j];
                                outv = ((la & 1) == 0) ? (v * cc - pv * sn)
                                                       : (pv * sn + v * cc);
                            } else outv = v;
                        }
                        outv *= QSCALE;
                        size_t idx = (((size_t)b * NH2 + H) * SEQ + s) * 48 + d;
                        unsigned short hh, mm2, ll;
                        split3(outv, hh, mm2, ll);
                        D0[idx] = hh; D1[idx] = mm2; D2[idx] = ll;
                    }
                }
            }
        }
}

// split-K x2 down-proj: z=0 -> C0 (k 0..511), z=1 -> C1 (k 512..1023)
__global__ __launch_bounds__(256) void gemm_down(
    const unsigned short* __restrict__ Ah, const unsigned short* __restrict__ Am,
    const unsigned short* __restrict__ Al,
    const unsigned short* __restrict__ Bh, const unsigned short* __restrict__ Bm,
    const unsigned short* __restrict__ Bl,
    float* __restrict__ C0, float* __restrict__ C1)
{
    __shared__ __align__(16) unsigned short LA[3 * 4096];
    __shared__ __align__(16) unsigned short LB[3 * 4096];
    int z = blockIdx.z;
    gemm3_body(LA, LB, Ah, Am, Al, Bh, Bm, Bl, z ? C1 : C0,
               nullptr, nullptr, nullptr, nullptr, nullptr, nullptr,
               R_TOT, 672, 1024, z * 512, z * 512 + 512, 0,
               blockIdx.y * 128, blockIdx.x * 128);
}

// merged kv-up (bx<16) + q-up (bx>=16)
__global__ __launch_bounds__(256) void gemm_up(
    const unsigned short* __restrict__ cnh, const unsigned short* __restrict__ cnm,
    const unsigned short* __restrict__ cnl,
    const unsigned short* __restrict__ Wuh, const unsigned short* __restrict__ Wum,
    const unsigned short* __restrict__ Wul,
    const unsigned short* __restrict__ qnh, const unsigned short* __restrict__ qnm,
    const unsigned short* __restrict__ qnl,
    const unsigned short* __restrict__ Wqh, const unsigned short* __restrict__ Wqm,
    const unsigned short* __restrict__ Wql,
    unsigned short* __restrict__ Kah, unsigned short* __restrict__ Kam,
    unsigned short* __restrict__ Kal, unsigned short* __restrict__ Va,
    unsigned short* __restrict__ Qah, unsigned short* __restrict__ Qam,
    unsigned short* __restrict__ Qal,
    const float* __restrict__ fcos, const float* __restrict__ fsin)
{
    __shared__ __align__(16) unsigned short LA[3 * 4096];
    __shared__ __align__(16) unsigned short LB[3 * 4096];
    bool isq = (blockIdx.x >= 16);
    if (!isq)
        gemm3_body(LA, LB, cnh, cnm, cnl, Wuh, Wum, Wul, nullptr,
                   Kah, Kam, Kal, Va, nullptr, nullptr,
                   R_TOT, 2048, 256, 0, 256, 1, blockIdx.y * 128, blockIdx.x * 128);
    else
        gemm3_body(LA, LB, qnh, qnm, qnl, Wqh, Wqm, Wql, nullptr,
                   Qah, Qam, Qal, nullptr, fcos, fsin,
                   R_TOT, 1536, 384, 0, 384, 2, blockIdx.y * 128, (blockIdx.x - 16) * 128);
}

// ---------------------------------------------------------------------------
// 1-plane bf16 GEMM (out-proj), frag-ordered LDS via global_load_lds.
// ---------------------------------------------------------------------------
__global__ __launch_bounds__(256) void gemm_out(
    const unsigned short* __restrict__ Ah, const unsigned short* __restrict__ Bh,
    float* __restrict__ C, int M, int N, int K)
{
    __shared__ __align__(16) unsigned short As[4096];
    __shared__ __align__(16) unsigned short Bs[4096];
    int tid = threadIdx.x;
    int wid = tid >> 6, lane = tid & 63;
    int la = lane & 15, lb = lane >> 4;
    int bm = blockIdx.y * 128, bn = blockIdx.x * 128;
    int wr = (wid >> 1) * 64, wc = (wid & 1) * 64;
    int wr4 = wr >> 4, wc4 = wc >> 4;

    int sg = tid >> 6, spos = tid & 63;
    int rowA0 = (sg << 4) + (spos & 15);
    int rowA1 = ((sg + 4) << 4) + (spos & 15);
    int kc = (spos >> 4) * 8;
    int wb = tid & 192;
    int grA0 = bm + rowA0; if (grA0 >= M) grA0 = M - 1;
    int grA1 = bm + rowA1; if (grA1 >= M) grA1 = M - 1;
    int gnB0 = bn + rowA0; if (gnB0 >= N) gnB0 = N - 1;
    int gnB1 = bn + rowA1; if (gnB1 >= N) gnB1 = N - 1;

    f32x4 acc[4][4];
#pragma unroll
    for (int m = 0; m < 4; ++m)
#pragma unroll
        for (int n = 0; n < 4; ++n) acc[m][n] = (f32x4){0.f, 0.f, 0.f, 0.f};
    for (int k0 = 0; k0 < K; k0 += 32) {
        __syncthreads();
        gl16(Ah + (size_t)grA0 * K + k0 + kc, &As[wb * 8]);
        gl16(Ah + (size_t)grA1 * K + k0 + kc, &As[(256 + wb) * 8]);
        gl16(Bh + (size_t)gnB0 * K + k0 + kc, &Bs[wb * 8]);
        gl16(Bh + (size_t)gnB1 * K + k0 + kc, &Bs[(256 + wb) * 8]);
        __syncthreads();
        bf16x8 a_[4], b_[4];
#pragma unroll
        for (int m = 0; m < 4; ++m) a_[m] = *(const bf16x8*)&As[((wr4 + m) * 64 + lane) * 8];
#pragma unroll
        for (int n = 0; n < 4; ++n) b_[n] = *(const bf16x8*)&Bs[((wc4 + n) * 64 + lane) * 8];
        __builtin_amdgcn_s_setprio(1);
#pragma unroll
        for (int m = 0; m < 4; ++m)
#pragma unroll
            for (int n = 0; n < 4; ++n) acc[m][n] = MFMA(a_[m], b_[n], acc[m][n]);
        __builtin_amdgcn_s_setprio(0);
    }
#pragma unroll
    for (int m = 0; m < 4; ++m)
#pragma unroll
        for (int n = 0; n < 4; ++n) {
            int gc = bn + wc + n * 16 + la;
            if (gc >= N) continue;
#pragma unroll
            for (int r = 0; r < 4; ++r) {
                int gr = bm + wr + m * 16 + lb * 4 + r;
                if (gr < M) C[(size_t)gr * N + gc] = acc[m][n][r];
            }
        }
}

// ---------------------------------------------------------------------------
// RMS-norm both streams (summing the two split-K partials) + K-rope 3-plane.
// ---------------------------------------------------------------------------
__global__ __launch_bounds__(256) void k_rmsrope3(
    const float* __restrict__ ckvqd, const float* __restrict__ ckvqd2,
    unsigned short* __restrict__ cnh, unsigned short* __restrict__ cnm,
    unsigned short* __restrict__ cnl,
    unsigned short* __restrict__ qnh, unsigned short* __restrict__ qnm,
    unsigned short* __restrict__ qnl,
    unsigned short* __restrict__ Kah, unsigned short* __restrict__ Kam,
    unsigned short* __restrict__ Kal,
    const float* __restrict__ gkv, const float* __restrict__ gq,
    const float* __restrict__ fcos, const float* __restrict__ fsin)
{
    __shared__ float red[256];
    __shared__ float rot[32];
    int row = blockIdx.x, tid = threadIdx.x;
    int b = row / SEQ, s = row - b * SEQ;
    const float* cp  = ckvqd  + (size_t)row * 672;
    const float* cp2 = ckvqd2 + (size_t)row * 672;
    float c0 = cp[tid] + cp2[tid];
    float q0 = cp[288 + tid] + cp2[288 + tid];
    float q1 = (tid < 128) ? (cp[544 + tid] + cp2[544 + tid]) : 0.f;

    red[tid] = c0 * c0;
    __syncthreads();
    for (int o = 128; o; o >>= 1) { if (tid < o) red[tid] += red[tid + o]; __syncthreads(); }
    float inv1 = rsqrtf(red[0] * (1.f / 256.f) + EPS_RMS);
    __syncthreads();
    red[tid] = q0 * q0 + q1 * q1;
    __syncthreads();
    for (int o = 128; o; o >>= 1) { if (tid < o) red[tid] += red[tid + o]; __syncthreads(); }
    float inv2 = rsqrtf(red[0] * (1.f / 384.f) + EPS_RMS);

    unsigned short h, m, l;
    split3(c0 * inv1 * gkv[tid], h, m, l);
    size_t ci = (size_t)row * 256 + tid;
    cnh[ci] = h; cnm[ci] = m; cnl[ci] = l;

    split3(q0 * inv2 * gq[tid], h, m, l);
    size_t qi = (size_t)row * 384 + tid;
    qnh[qi] = h; qnm[qi] = m; qnl[qi] = l;
    if (tid < 128) {
        split3(q1 * inv2 * gq[256 + tid], h, m, l);
        qnh[qi + 256] = h; qnm[qi + 256] = m; qnl[qi + 256] = l;
    }

    if (tid < 16) {
        float r0 = cp[256 + 2 * tid] + cp2[256 + 2 * tid];
        float r1 = cp[256 + 2 * tid + 1] + cp2[256 + 2 * tid + 1];
        float o0, o1;
        if (s == 0) { o0 = r0; o1 = r1; }
        else {
            int p = (s - 1) & 255;
            int j = tid & 7;
            float cc = fcos[p * 8 + j], sn = fsin[p * 8 + j];
            o0 = r0 * cc - r1 * sn;
            o1 = r0 * sn + r1 * cc;
        }
        rot[2 * tid] = o0; rot[2 * tid + 1] = o1;
    }
    __syncthreads();
    for (int t = tid; t < 512; t += 256) {
        int H = t >> 4, dd = t & 15;
        int e = H & 1;
        split3(rot[e * 16 + dd], h, m, l);
        size_t idx = (((size_t)b * NH2 + H) * SEQ + s) * 48 + 32 + dd;
        Kah[idx] = h; Kam[idx] = m; Kal[idx] = l;
    }
}

// ---------------------------------------------------------------------------
// MFMA cog-attention v14 = v13 with the Pl swizzle re-expressed in
// base+immediate form: write index = pbn(compile-time) + pwg[g]
// (4 hoisted per-thread constants; XOR commutes out since pswz bits 3-4
// never interact with carries). Removes the round-18 register-pressure
// spill while keeping 0 bank conflicts and the exp2 softmax.
// ---------------------------------------------------------------------------
__global__ __launch_bounds__(256, 2) void k_attn14(
    const unsigned short* __restrict__ Qah, const unsigned short* __restrict__ Qam,
    const unsigned short* __restrict__ Qal,
    const unsigned short* __restrict__ Kah, const unsigned short* __restrict__ Kam,
    const unsigned short* __restrict__ Kal,
    const unsigned short* __restrict__ Va, const float* __restrict__ ghead,
    const float* __restrict__ lq1, const float* __restrict__ lk1,
    const float* __restrict__ lq2, const float* __restrict__ lk2,
    unsigned short* __restrict__ attO)
{
    __shared__ __align__(16) unsigned short KS[6][3072];
    __shared__ __align__(16) unsigned short Vt[4096];
    __shared__ __align__(16) unsigned short Pl[4][1024];

    int bid0 = blockIdx.x;
    int bid = (bid0 & 7) * 68 + (bid0 >> 3);   // bijective XCD swizzle (544=8*68)
    int rt = bid % 17;
    int bh = bid / 17;
    int h = bh & 15, b = bh >> 4;
    int tid = threadIdx.x, wid = tid >> 6, lane = tid & 63;
    int la = lane & 15, lb = lane >> 4;
    int r0 = rt * 64, r0w = r0 + wid * 16;

    // Pl swizzle (block P = L ^ ((L>>3)&3)) in base+immediate form:
    // write idx = pbn + pwg[g], pbn = (n>>1)*512 + ((n&1)<<1)*128 (imm)
    int pswz = ((((la >> 3) << 1) | (lb >> 1)) << 3);
    int pwg[4];
#pragma unroll
    for (int g = 0; g < 4; ++g)
        pwg[g] = (((lb * 4 + g) * 8) ^ pswz) + (la & 7) + ((la >> 3) << 7);
    int prd = (lane * 8) ^ (((lane >> 3) & 3) << 3);    // read offset (both halves)

    float e1 = 0.f, e2 = 0.f;
    for (int i = 0; i < 32; ++i) { e1 = fmaf(lq1[i], lk1[i], e1); e2 = fmaf(lq2[i], lk2[i], e2); }
    float lam = __expf(e1) - __expf(e2) + LAMBDA_INIT;

    int pr[4];
#pragma unroll
    for (int g = 0; g < 4; ++g) {
        int r = r0w + lb * 4 + g;
        pr[g] = (r >= 1 && r < SEQ) ? ((r - 1) & 255) : -1;
    }
    int rA = r0w + la;
    int prA = (rA >= 1 && rA < SEQ) ? ((rA - 1) & 255) : -1;

    int prm = -1;
    for (int i = 0; i < 64; ++i) {
        int r = r0 + i;
        if (r >= 1 && r < SEQ) { int p = (r - 1) & 255; prm = p > prm ? p : prm; }
    }

    const size_t hb1 = ((size_t)(b * NH2 + 2 * h)) * SEQ * 48;
    const size_t hb2 = ((size_t)(b * NH2 + 2 * h + 1)) * SEQ * 48;
    const unsigned short* vg = Va + ((size_t)(b * NHEAD + h)) * NVT * 4096;
    const unsigned short* KP[6] = {Kah + hb1, Kam + hb1, Kal + hb1,
                                   Kah + hb2, Kam + hb2, Kal + hb2};

    int qrow = r0w + la; if (qrow > SEQ - 1) qrow = SEQ - 1;
    bf16x8 zf;
#pragma unroll
    for (int u = 0; u < 8; ++u) zf[u] = 0;
    bf16x8 q1[3][2], q2[3][2];
    {
        const unsigned short* QPl[3] = {Qah, Qam, Qal};
#pragma unroll
        for (int p = 0; p < 3; ++p)
#pragma unroll
            for (int f = 0; f < 2; ++f) {
                if (f == 0 || lb < 2) {
                    q1[p][f] = *(const bf16x8*)(QPl[p] + hb1 + (size_t)qrow * 48 + 32 * f + lb * 8);
                    q2[p][f] = *(const bf16x8*)(QPl[p] + hb2 + (size_t)qrow * 48 + 32 * f + lb * 8);
                } else { q1[p][f] = zf; q2[p][f] = zf; }
            }
    }

    // K staging chunk map: ci -> (col, k-octet u)
    int colA, uA, colB = 0, uB = 0;
    {
        int ci = tid;
        colA = ((ci >> 6) << 4) + (ci & 15);
        uA = (ci >> 4) & 3;
        if (tid < 128) {
            int c2 = tid;
            colB = ((c2 >> 5) << 4) + (c2 & 15);
            uB = 4 + ((c2 >> 4) & 1);
        }
    }

    i32x4 preA[6], preB[6], vv[2];
    auto LOADT = [&](int c0n) {
        int gcA = c0n + colA; if (gcA > SEQ - 1) gcA = SEQ - 1;
#pragma unroll
        for (int p = 0; p < 6; ++p)
            preA[p] = *(const i32x4*)(KP[p] + (size_t)gcA * 48 + uA * 8);
        if (tid < 128) {
            int gcB = c0n + colB; if (gcB > SEQ - 1) gcB = SEQ - 1;
#pragma unroll
            for (int p = 0; p < 6; ++p)
                preB[p] = *(const i32x4*)(KP[p] + (size_t)gcB * 48 + uB * 8);
        }
        const unsigned short* vt = vg + (size_t)(c0n >> 6) * 4096;
        vv[0] = *(const i32x4*)(vt + tid * 8);
        vv[1] = *(const i32x4*)(vt + 2048 + tid * 8);
    };
    auto WRITET = [&]() {
#pragma unroll
        for (int p = 0; p < 6; ++p)
            *(i32x4*)&KS[p][tid * 8] = preA[p];          // linear, conflict-free
        if (tid < 128) {
#pragma unroll
            for (int p = 0; p < 6; ++p)
                *(i32x4*)&KS[p][2048 + tid * 8] = preB[p];
        }
        *(i32x4*)&Vt[tid * 8] = vv[0];                   // linear, conflict-free
        *(i32x4*)&Vt[2048 + tid * 8] = vv[1];
    };

    f32x4 O1[4], O2[4], VS[4];
#pragma unroll
    for (int nd = 0; nd < 4; ++nd) {
        O1[nd] = (f32x4){0.f, 0.f, 0.f, 0.f};
        O2[nd] = (f32x4){0.f, 0.f, 0.f, 0.f};
        VS[nd] = (f32x4){0.f, 0.f, 0.f, 0.f};
    }
    float dA1[4] = {0.f, 0.f, 0.f, 0.f}, dA2[4] = {0.f, 0.f, 0.f, 0.f};
    float gsA[4] = {0.f, 0.f, 0.f, 0.f};
    f32x4 z = (f32x4){0.f, 0.f, 0.f, 0.f};

    LOADT(0);
    WRITET();
    __syncthreads();

    for (int j = 0; j <= 16; ++j) {
        bool need = (j == 16) ? (prm >= 255)
                              : (((j & 3) == 0) || (prm >= 64 * (j & 3) - 1));
        if (!need) continue;
        int c0 = j * 64;

        int nj = -1;
        for (int t2 = j + 1; t2 <= 16; ++t2) {
            bool nd2 = (t2 == 16) ? (prm >= 255)
                                  : (((t2 & 3) == 0) || (prm >= 64 * (t2 & 3) - 1));
            if (nd2) { nj = t2; break; }
        }
        if (nj >= 0) LOADT(nj * 64);

        // ---- scores S1 / S2 (packed-layout frag reads) ----
        f32x4 s1[4], s2[4];
        __builtin_amdgcn_s_setprio(1);
#pragma unroll
        for (int n = 0; n < 4; ++n) {
            int g0 = n * 512 + lane * 8;
            int g1 = 2048 + n * 256 + (lane & 31) * 8;
            bf16x8 kh0 = *(const bf16x8*)&KS[0][g0];
            bf16x8 kh1 = *(const bf16x8*)&KS[0][g1];
            bf16x8 km0 = *(const bf16x8*)&KS[1][g0];
            bf16x8 km1 = *(const bf16x8*)&KS[1][g1];
            bf16x8 kl0 = *(const bf16x8*)&KS[2][g0];
            bf16x8 kl1 = *(const bf16x8*)&KS[2][g1];
            f32x4 s = z;
            s = MFMA(q1[0][0], kh0, s); s = MFMA(q1[0][1], kh1, s);
            s = MFMA(q1[0][0], km0, s); s = MFMA(q1[0][1], km1, s);
            s = MFMA(q1[1][0], kh0, s); s = MFMA(q1[1][1], kh1, s);
            s = MFMA(q1[0][0], kl0, s); s = MFMA(q1[0][1], kl1, s);
            s = MFMA(q1[1][0], km0, s); s = MFMA(q1[1][1], km1, s);
            s = MFMA(q1[2][0], kh0, s); s = MFMA(q1[2][1], kh1, s);
            s1[n] = s;
        }
#pragma unroll
        for (int n = 0; n < 4; ++n) {
            int g0 = n * 512 + lane * 8;
            int g1 = 2048 + n * 256 + (lane & 31) * 8;
            bf16x8 kh0 = *(const bf16x8*)&KS[3][g0];
            bf16x8 kh1 = *(const bf16x8*)&KS[3][g1];
            bf16x8 km0 = *(const bf16x8*)&KS[4][g0];
            bf16x8 km1 = *(const bf16x8*)&KS[4][g1];
            bf16x8 kl0 = *(const bf16x8*)&KS[5][g0];
            bf16x8 kl1 = *(const bf16x8*)&KS[5][g1];
            f32x4 s = z;
            s = MFMA(q2[0][0], kh0, s); s = MFMA(q2[0][1], kh1, s);
            s = MFMA(q2[0][0], km0, s); s = MFMA(q2[0][1], km1, s);
            s = MFMA(q2[1][0], kh0, s); s = MFMA(q2[1][1], kh1, s);
            s = MFMA(q2[0][0], kl0, s); s = MFMA(q2[0][1], kl1, s);
            s = MFMA(q2[1][0], km0, s); s = MFMA(q2[1][1], km1, s);
            s = MFMA(q2[2][0], kh0, s); s = MFMA(q2[2][1], kh1, s);
            s2[n] = s;
        }
        __builtin_amdgcn_s_setprio(0);

        // ---- slim no-max signed softmax (exp2; log2e pre-folded into Q) ----
        unsigned short p1v[4][4], p2v[4][4];
#pragma unroll
        for (int n = 0; n < 4; ++n) {
            int c = c0 + n * 16 + la;
            bool cz = (c == 0);
            int cm = (c - 1) & 255;
            bool cin = (c < SEQ);
#pragma unroll
            for (int g = 0; g < 4; ++g) {
                bool al = cz || (cin && cm <= pr[g]);
                float a = s1[n][g];
                float sa = __builtin_copysignf(__builtin_amdgcn_exp2f(fabsf(a)), a);
                sa = al ? sa : 0.f;
                p1v[n][g] = (unsigned short)((__float_as_uint(sa) + 0x8000u) >> 16);
                gsA[g] += sa;
                dA1[g] += fabsf(sa);
                float bb = s2[n][g];
                float sb = __builtin_copysignf(__builtin_amdgcn_exp2f(fabsf(bb)), bb);
                sb = al ? sb : 0.f;
                p2v[n][g] = (unsigned short)((__float_as_uint(sb) + 0x8000u) >> 16);
                dA2[g] += fabsf(sb);
            }
        }

        // ---- P1 -> A-frags via wave-private swizzled LDS (base+imm form) ----
#pragma unroll
        for (int n = 0; n < 4; ++n) {
            int pbn = (n >> 1) * 512 + ((n & 1) << 1) * 128;   // compile-time
#pragma unroll
            for (int g = 0; g < 4; ++g)
                Pl[wid][pbn + pwg[g]] = p1v[n][g];
        }
        __asm__ volatile("s_waitcnt lgkmcnt(0)" ::: "memory");
        __builtin_amdgcn_sched_barrier(0);
        bf16x8 p1a0 = *(const bf16x8*)&Pl[wid][prd];
        bf16x8 p1a1 = *(const bf16x8*)&Pl[wid][512 + prd];
#pragma unroll
        for (int n = 0; n < 4; ++n) {
            int pbn = (n >> 1) * 512 + ((n & 1) << 1) * 128;
#pragma unroll
            for (int g = 0; g < 4; ++g)
                Pl[wid][pbn + pwg[g]] = p2v[n][g];
        }
        __asm__ volatile("s_waitcnt lgkmcnt(0)" ::: "memory");
        __builtin_amdgcn_sched_barrier(0);
        bf16x8 p2a0 = *(const bf16x8*)&Pl[wid][prd];
        bf16x8 p2a1 = *(const bf16x8*)&Pl[wid][512 + prd];

        // mask-frags for Vsum
        bf16x8 p0[2];
#pragma unroll
        for (int f = 0; f < 2; ++f)
#pragma unroll
            for (int jb = 0; jb < 8; ++jb) {
                int c = c0 + 32 * f + lb * 8 + jb;
                bool al = (c == 0) || (c < SEQ && ((c - 1) & 255) <= prA);
                p0[f][jb] = al ? (short)0x3F80 : (short)0;
            }

        // ---- PV + VS ----
        __builtin_amdgcn_s_setprio(1);
#pragma unroll
        for (int nd = 0; nd < 4; ++nd) {
            bf16x8 vb0 = *(const bf16x8*)&Vt[(nd * 2) * 512 + lane * 8];
            bf16x8 vb1 = *(const bf16x8*)&Vt[(nd * 2 + 1) * 512 + lane * 8];
            O1[nd] = MFMA(p1a0, vb0, O1[nd]);
            O1[nd] = MFMA(p1a1, vb1, O1[nd]);
            O2[nd] = MFMA(p2a0, vb0, O2[nd]);
            O2[nd] = MFMA(p2a1, vb1, O2[nd]);
            VS[nd] = MFMA(p0[0], vb0, VS[nd]);
            VS[nd] = MFMA(p0[1], vb1, VS[nd]);
        }
        __builtin_amdgcn_s_setprio(0);

        if (nj >= 0) {
            __syncthreads();
            WRITET();
            __syncthreads();
        }
    }

    // ---- final reductions ----
#pragma unroll
    for (int off = 1; off < 16; off <<= 1) {
#pragma unroll
        for (int g = 0; g < 4; ++g) {
            dA1[g] += __shfl_xor(dA1[g], off);
            dA2[g] += __shfl_xor(dA2[g], off);
            gsA[g] += __shfl_xor(gsA[g], off);
        }
    }

    float i1[4], i2g[4], Gl[4];
#pragma unroll
    for (int g = 0; g < 4; ++g) {
        i1[g] = 1.f / dA1[g];
        i2g[g] = 1.f / dA2[g];
        Gl[g] = gsA[g] * i1[g] * (1.f / (float)SEQ) * lam;
    }
    f32x4 outv[4];
#pragma unroll
    for (int nd = 0; nd < 4; ++nd)
#pragma unroll
        for (int g = 0; g < 4; ++g)
            outv[nd][g] = O1[nd][g] * i1[g] - lam * i2g[g] * O2[nd][g] + Gl[g] * VS[nd][g];

    float ssq[4] = {0.f, 0.f, 0.f, 0.f};
#pragma unroll
    for (int nd = 0; nd < 4; ++nd)
#pragma unroll
        for (int g = 0; g < 4; ++g) ssq[g] += outv[nd][g] * outv[nd][g];
#pragma unroll
    for (int off = 1; off < 16; off <<= 1)
#pragma unroll
        for (int g = 0; g < 4; ++g) ssq[g] += __shfl_xor(ssq[g], off);
    float inv[4];
#pragma unroll
    for (int g = 0; g < 4; ++g) inv[g] = rsqrtf(ssq[g] * (1.f / 64.f) + EPS_HEAD);

#pragma unroll
    for (int nd = 0; nd < 4; ++nd) {
        int d = nd * 16 + la;
        float gv = ghead[d];
#pragma unroll
        for (int g = 0; g < 4; ++g) {
            int r = r0w + lb * 4 + g;
            if (r < SEQ)
                attO[(((size_t)b * SEQ + r) * NHEAD + h) * 64 + d] =
                    f2bf(outv[nd][g] * inv[g] * gv);
        }
    }
}

// ---------------------------------------------------------------------------
extern "C" void kernel_launch(void* const* d_in, const int* in_sizes, int n_in,
                              void* d_out, int out_size, void* d_ws, size_t ws_size,
                              hipStream_t stream)
{
    const float* x    = (const float*)d_in[0];
    const float* fcos = (const float*)d_in[2];
    const float* fsin = (const float*)d_in[3];
    const float* Wkvd = (const float*)d_in[4];
    const float* Wqd  = (const float*)d_in[5];
    const float* Wkvu = (const float*)d_in[6];
    const float* Wqu  = (const float*)d_in[7];
    const float* Wo   = (const float*)d_in[8];
    const float* gkv  = (const float*)d_in[9];
    const float* gq   = (const float*)d_in[10];
    const float* gh   = (const float*)d_in[11];
    const float* lq1  = (const float*)d_in[12];
    const float* lk1  = (const float*)d_in[13];
    const float* lq2  = (const float*)d_in[14];
    const float* lk2  = (const float*)d_in[15];
    float* out = (float*)d_out;

    const int R = R_TOT;  // 2050
    char* base = (char*)d_ws;
    size_t off = 0;
    auto alloc = [&](size_t bytes) -> char* {
        char* p = base + off;
        off = (off + bytes + 255) & ~(size_t)255;
        return p;
    };
    const size_t KPL = (size_t)BATCH * NH2 * SEQ * 48 * 2;   // per K/Q plane
    const size_t VAB = (size_t)BATCH * NHEAD * NVT * 4096 * 2;  // tiled Vt

    unsigned short* xh = (unsigned short*)alloc((size_t)R * 1024 * 2);
    unsigned short* xm = (unsigned short*)alloc((size_t)R * 1024 * 2);
    unsigned short* xl = (unsigned short*)alloc((size_t)R * 1024 * 2);
    unsigned short* attO = xh;                      // x dead after down-GEMM
    unsigned short* Kah  = xm;                      // KPL fits xm+xl

    float* ckvqd = (float*)alloc((size_t)R * 672 * 4);
    unsigned short* cnh = (unsigned short*)alloc((size_t)R * 256 * 2);
    unsigned short* cnm = (unsigned short*)alloc((size_t)R * 256 * 2);
    unsigned short* cnl = (unsigned short*)alloc((size_t)R * 256 * 2);
    unsigned short* qnh = (unsigned short*)alloc((size_t)R * 384 * 2);
    unsigned short* qnm = (unsigned short*)alloc((size_t)R * 384 * 2);
    unsigned short* qnl = (unsigned short*)alloc((size_t)R * 384 * 2);
    unsigned short* Kam = (unsigned short*)alloc(KPL);
    unsigned short* Kal = (unsigned short*)alloc(KPL);
    unsigned short* Qah = (unsigned short*)alloc(KPL);
    unsigned short* Qam = (unsigned short*)alloc(KPL);
    unsigned short* Qal = (unsigned short*)alloc(KPL);
    unsigned short* Va  = (unsigned short*)alloc(VAB);
    unsigned short* Wdh = (unsigned short*)alloc((size_t)672 * 1024 * 2);
    unsigned short* Wdm = (unsigned short*)alloc((size_t)672 * 1024 * 2);
    unsigned short* Wdl = (unsigned short*)alloc((size_t)672 * 1024 * 2);
    unsigned short* Wuh = (unsigned short*)alloc((size_t)2048 * 256 * 2);
    unsigned short* Wum = (unsigned short*)alloc((size_t)2048 * 256 * 2);
    unsigned short* Wul = (unsigned short*)alloc((size_t)2048 * 256 * 2);
    unsigned short* Wqh = (unsigned short*)alloc((size_t)1536 * 384 * 2);
    unsigned short* Wqm = (unsigned short*)alloc((size_t)1536 * 384 * 2);
    unsigned short* Wql = (unsigned short*)alloc((size_t)1536 * 384 * 2);
    unsigned short* Wo1 = (unsigned short*)alloc((size_t)1024 * 1024 * 2);

    // split-K partial #2 for down-proj: aliases Qah (dead until gemm_up).
    float* ckvqd2 = (float*)Qah;

    dim3 blk(256);
    conv_all<<<4834, blk, 0, stream>>>(x, Wkvd, Wqd, Wkvu, Wqu, Wo,
        xh, xm, xl, Wdh, Wdm, Wdl, Wuh, Wum, Wul, Wqh, Wqm, Wql, Wo1);
    gemm_down<<<dim3(6, 17, 2), blk, 0, stream>>>(xh, xm, xl, Wdh, Wdm, Wdl,
                                                  ckvqd, ckvqd2);
    k_rmsrope3<<<R, blk, 0, stream>>>(ckvqd, ckvqd2, cnh, cnm, cnl, qnh, qnm, qnl,
                                      Kah, Kam, Kal, gkv, gq, fcos, fsin);
    // zero Va so tile-16 padding cols (>=SEQ) are 0 (they multiply P=0 anyway)
    hipMemsetAsync(Va, 0, VAB, stream);
    gemm_up<<<dim3(28, 17), blk, 0, stream>>>(cnh, cnm, cnl, Wuh, Wum, Wul,
        qnh, qnm, qnl, Wqh, Wqm, Wql, Kah, Kam, Kal, Va, Qah, Qam, Qal, fcos, fsin);
    k_attn14<<<544, blk, 0, stream>>>(Qah, Qam, Qal, Kah, Kam, Kal,
        Va, gh, lq1, lk1, lq2, lk2, attO);
    gemm_out<<<dim3(8, 17), blk, 0, stream>>>(attO, Wo1, out, R, 1024, 1024);
}

// Round 20
// 261.747 us; speedup vs baseline: 1.0636x; 1.0219x over previous
//
#include <hip/hip_runtime.h>
#include <hip/hip_bf16.h>
#include <math.h>

#define NHEAD 16
#define SEQ 1025
#define BATCH 2
#define NH2 32
#define KSCALE (1.0f/48.0f)
#define QSCALE (KSCALE * 1.4426950408889634f)   // fold log2(e): exp(|S|)=exp2(|S'|)
#define EPS_RMS 1.1920929e-07f
#define EPS_HEAD 1e-05f
#define LAMBDA_INIT 0.2f
#define R_TOT (BATCH*SEQ)
#define NVT 17              // V tiles per head (ceil(SEQ/64))

typedef __attribute__((ext_vector_type(8))) short bf16x8;
typedef __attribute__((ext_vector_type(4))) float f32x4;
typedef __attribute__((ext_vector_type(4))) int  i32x4;

static __device__ __forceinline__ unsigned short f2bf(float x) {
    unsigned int u = __float_as_uint(x);
    unsigned int r = (u + 0x7fffu + ((u >> 16) & 1u)) >> 16;
    return (unsigned short)r;
}
static __device__ __forceinline__ float bf2f(unsigned short h) {
    return __uint_as_float(((unsigned int)h) << 16);
}
static __device__ __forceinline__ void split3(float v, unsigned short& h,
                                              unsigned short& m, unsigned short& l) {
    h = f2bf(v); float r1 = v - bf2f(h);
    m = f2bf(r1); float r2 = r1 - bf2f(m);
    l = f2bf(r2);
}
static __device__ __forceinline__ f32x4 MFMA(bf16x8 a, bf16x8 b, f32x4 c) {
    return __builtin_amdgcn_mfma_f32_16x16x32_bf16(a, b, c, 0, 0, 0);
}
// async global->LDS, 16B per lane; LDS dest = wave-uniform base + lane*16
static __device__ __forceinline__ void gl16(const unsigned short* g,
                                            unsigned short* l) {
    __builtin_amdgcn_global_load_lds(
        (const __attribute__((address_space(1))) void*)g,
        (__attribute__((address_space(3))) void*)l, 16, 0, 0);
}

// ---------------------------------------------------------------------------
// ONE conversion kernel: x 3-split + 4 weights 3-split-transpose + Wo 1-plane.
// ---------------------------------------------------------------------------
__global__ __launch_bounds__(256) void conv_all(
    const float* __restrict__ x, const float* __restrict__ Wkvd,
    const float* __restrict__ Wqd, const float* __restrict__ Wkvu,
    const float* __restrict__ Wqu, const float* __restrict__ Wo,
    unsigned short* __restrict__ xh, unsigned short* __restrict__ xm,
    unsigned short* __restrict__ xl,
    unsigned short* __restrict__ Wdh, unsigned short* __restrict__ Wdm,
    unsigned short* __restrict__ Wdl,
    unsigned short* __restrict__ Wuh, unsigned short* __restrict__ Wum,
    unsigned short* __restrict__ Wul,
    unsigned short* __restrict__ Wqh, unsigned short* __restrict__ Wqm,
    unsigned short* __restrict__ Wql,
    unsigned short* __restrict__ Wo1)
{
    __shared__ float tile[32][33];
    int bid = blockIdx.x, tid = threadIdx.x;
    if (bid < 2050) {
        int i = bid * 1024 + tid * 4;
        f32x4 v = *(const f32x4*)(x + i);
#pragma unroll
        for (int j = 0; j < 4; ++j) {
            unsigned short h, m, l;
            split3(v[j], h, m, l);
            xh[i + j] = h; xm[i + j] = m; xl[i + j] = l;
        }
        return;
    }
    bid -= 2050;
    const float* W; unsigned short *Th, *Tm, *Tl; int K, N, gx;
    if (bid < 288)              { W = Wkvd; Th = Wdh; Tm = Wdm; Tl = Wdl; K = 1024; N = 288;  gx = 9;  }
    else if ((bid -= 288) < 384){ W = Wqd;  Th = Wdh + (size_t)288*1024; Tm = Wdm + (size_t)288*1024;
                                  Tl = Wdl + (size_t)288*1024; K = 1024; N = 384; gx = 12; }
    else if ((bid -= 384) < 512){ W = Wkvu; Th = Wuh; Tm = Wum; Tl = Wul; K = 256;  N = 2048; gx = 64; }
    else if ((bid -= 512) < 576){ W = Wqu;  Th = Wqh; Tm = Wqm; Tl = Wql; K = 384;  N = 1536; gx = 48; }
    else { bid -= 576;            W = Wo;   Th = Wo1; Tm = nullptr; Tl = nullptr; K = 1024; N = 1024; gx = 32; }

    int n0 = (bid % gx) * 32, k0 = (bid / gx) * 32;
    int tx = tid & 31, ty = tid >> 5;
    for (int kk = ty; kk < 32; kk += 8)
        tile[kk][tx] = W[(size_t)(k0 + kk) * N + n0 + tx];
    __syncthreads();
    for (int nn = ty; nn < 32; nn += 8) {
        int n = n0 + nn, k = k0 + tx;
        float v = tile[tx][nn];
        if (Tm) {
            unsigned short h, m, l;
            split3(v, h, m, l);
            Th[(size_t)n * K + k] = h;
            Tm[(size_t)n * K + k] = m;
            Tl[(size_t)n * K + k] = l;
        } else {
            Th[(size_t)n * K + k] = f2bf(v);
        }
    }
}

// ---------------------------------------------------------------------------
// 3-way split MFMA GEMM body, frag-ordered LDS staged via global_load_lds
// (width=16; OOB rows clamped — garbage never stored). [kb,ke) K-range.
// epi==1 writes V in TILED-TRANSPOSED layout (attention's Vt LDS layout).
// epi==2 scales Q by QSCALE (KSCALE * log2(e)) for exp2-based softmax.
// ---------------------------------------------------------------------------
__device__ __forceinline__ void gemm3_body(
    unsigned short* LA, unsigned short* LB,
    const unsigned short* __restrict__ Ah, const unsigned short* __restrict__ Am,
    const unsigned short* __restrict__ Al,
    const unsigned short* __restrict__ Bh, const unsigned short* __restrict__ Bm,
    const unsigned short* __restrict__ Bl,
    float* __restrict__ C,
    unsigned short* __restrict__ D0, unsigned short* __restrict__ D1,
    unsigned short* __restrict__ D2, unsigned short* __restrict__ D3,
    const float* __restrict__ fcos, const float* __restrict__ fsin,
    int M, int N, int K, int kb, int ke, int epi, int bm, int bn)
{
    int tid = threadIdx.x;
    int wid = tid >> 6, lane = tid & 63;
    int la = lane & 15, lb = lane >> 4;
    int wr = (wid >> 1) * 64, wc = (wid & 1) * 64;
    int wr4 = wr >> 4, wc4 = wc >> 4;

    const unsigned short* APl[3] = {Ah, Am, Al};
    const unsigned short* BPl[3] = {Bh, Bm, Bl};

    // staging coords (fixed per thread): row/kc within the 128x32 tile
    int sg = tid >> 6, spos = tid & 63;
    int rowA0 = (sg << 4) + (spos & 15);          // it = 0
    int rowA1 = ((sg + 4) << 4) + (spos & 15);    // it = 1
    int kc = (spos >> 4) * 8;
    int wb = tid & 192;                           // wave-uniform LDS chunk base

    f32x4 acc[4][4];
#pragma unroll
    for (int m = 0; m < 4; ++m)
#pragma unroll
        for (int n = 0; n < 4; ++n) acc[m][n] = (f32x4){0.f, 0.f, 0.f, 0.f};

    auto LDF = [&](bf16x8* dst, const unsigned short* Lb, int p, int rb) {
#pragma unroll
        for (int q = 0; q < 4; ++q)
            dst[q] = *(const bf16x8*)&Lb[p * 4096 + ((rb + q) * 64 + lane) * 8];
    };
    auto MM = [&](bf16x8* av, bf16x8* bv) {
#pragma unroll
        for (int m = 0; m < 4; ++m)
#pragma unroll
            for (int n = 0; n < 4; ++n)
                acc[m][n] = MFMA(av[m], bv[n], acc[m][n]);
    };

    int grA0 = bm + rowA0; if (grA0 >= M) grA0 = M - 1;
    int grA1 = bm + rowA1; if (grA1 >= M) grA1 = M - 1;
    int gnB0 = bn + rowA0; if (gnB0 >= N) gnB0 = N - 1;
    int gnB1 = bn + rowA1; if (gnB1 >= N) gnB1 = N - 1;

    for (int k0 = kb; k0 < ke; k0 += 32) {
        __syncthreads();   // previous-tile reads complete before overwrite
#pragma unroll
        for (int p = 0; p < 3; ++p) {
            gl16(APl[p] + (size_t)grA0 * K + k0 + kc, &LA[p * 4096 + wb * 8]);
            gl16(APl[p] + (size_t)grA1 * K + k0 + kc, &LA[p * 4096 + (256 + wb) * 8]);
            gl16(BPl[p] + (size_t)gnB0 * K + k0 + kc, &LB[p * 4096 + wb * 8]);
            gl16(BPl[p] + (size_t)gnB1 * K + k0 + kc, &LB[p * 4096 + (256 + wb) * 8]);
        }
        __syncthreads();   // compiler drains vmcnt before barrier
        bf16x8 av[4], bv0[4], bv1[4], bvt[4];
        LDF(av, LA, 0, wr4); LDF(bv0, LB, 0, wc4);
        LDF(bv1, LB, 1, wc4); LDF(bvt, LB, 2, wc4);
        __builtin_amdgcn_s_setprio(1);
        MM(av, bv0); MM(av, bv1); MM(av, bvt);   // hh hm hl
        __builtin_amdgcn_s_setprio(0);
        LDF(bvt, LA, 1, wr4);
        __builtin_amdgcn_s_setprio(1);
        MM(bvt, bv0); MM(bvt, bv1);              // mh mm
        __builtin_amdgcn_s_setprio(0);
        LDF(bvt, LA, 2, wr4);
        __builtin_amdgcn_s_setprio(1);
        MM(bvt, bv0);                            // lh
        __builtin_amdgcn_s_setprio(0);
    }

#pragma unroll
    for (int m = 0; m < 4; ++m)
#pragma unroll
        for (int n = 0; n < 4; ++n) {
            int gc = bn + wc + n * 16 + la;
#pragma unroll
            for (int r = 0; r < 4; ++r) {
                int gr = bm + wr + m * 16 + lb * 4 + r;
                float v = acc[m][n][r];
                if (epi == 0) {
                    if (gr < M && gc < N) C[(size_t)gr * N + gc] = v;
                } else if (epi == 1) {
                    if (gr < M) {
                        int b = gr / SEQ, s = gr - b * SEQ;
                        int h2 = gc >> 7, rem = gc & 127;
                        if (rem < 64) {
                            int H = 2 * h2 + (rem >> 5), d = rem & 31;
                            size_t idx = (((size_t)b * NH2 + H) * SEQ + s) * 48 + d;
                            unsigned short hh, mm2, ll;
                            split3(v, hh, mm2, ll);
                            D0[idx] = hh; D1[idx] = mm2; D2[idx] = ll;
                        } else {
                            // V in tiled-transposed (attention Vt) layout
                            int d = rem - 64;
                            int cv = s & 63;
                            int g = ((d >> 4) << 1) + (cv >> 5);
                            int pos = (((cv & 31) >> 3) << 4) + (d & 15);
                            D3[(((size_t)b * NHEAD + h2) * NVT + (s >> 6)) * 4096
                               + g * 512 + pos * 8 + (cv & 7)] = f2bf(v);
                        }
                    }
                } else {
                    float pv = __shfl_xor(v, 1);   // before any guard
                    if (gr < M) {
                        int b = gr / SEQ, s = gr - b * SEQ;
                        int h2 = gc / 96, rem = gc - h2 * 96;
                        int H, d; float outv;
                        if (rem < 64) {
                            H = 2 * h2 + (rem >> 5); d = rem & 31; outv = v;
                        } else {
                            int dd = rem - 64;
                            int e = dd >> 4, j = (dd & 15) >> 1;
                            H = 2 * h2 + e; d = 32 + (dd & 15);
                            if (s != 0) {
                                int p = (s - 1) & 255;
                                float cc = fcos[p * 8 + j], sn = fsin[p * 8 + j];
                                outv = ((la & 1) == 0) ? (v * cc - pv * sn)
                                                       : (pv * sn + v * cc);
                            } else outv = v;
                        }
                        outv *= QSCALE;
                        size_t idx = (((size_t)b * NH2 + H) * SEQ + s) * 48 + d;
                        unsigned short hh, mm2, ll;
                        split3(outv, hh, mm2, ll);
                        D0[idx] = hh; D1[idx] = mm2; D2[idx] = ll;
                    }
                }
            }
        }
}

// split-K x2 down-proj: z=0 -> C0 (k 0..511), z=1 -> C1 (k 512..1023)
__global__ __launch_bounds__(256) void gemm_down(
    const unsigned short* __restrict__ Ah, const unsigned short* __restrict__ Am,
    const unsigned short* __restrict__ Al,
    const unsigned short* __restrict__ Bh, const unsigned short* __restrict__ Bm,
    const unsigned short* __restrict__ Bl,
    float* __restrict__ C0, float* __restrict__ C1)
{
    __shared__ __align__(16) unsigned short LA[3 * 4096];
    __shared__ __align__(16) unsigned short LB[3 * 4096];
    int z = blockIdx.z;
    gemm3_body(LA, LB, Ah, Am, Al, Bh, Bm, Bl, z ? C1 : C0,
               nullptr, nullptr, nullptr, nullptr, nullptr, nullptr,
               R_TOT, 672, 1024, z * 512, z * 512 + 512, 0,
               blockIdx.y * 128, blockIdx.x * 128);
}

// merged kv-up (bx<16) + q-up (bx>=16)
__global__ __launch_bounds__(256) void gemm_up(
    const unsigned short* __restrict__ cnh, const unsigned short* __restrict__ cnm,
    const unsigned short* __restrict__ cnl,
    const unsigned short* __restrict__ Wuh, const unsigned short* __restrict__ Wum,
    const unsigned short* __restrict__ Wul,
    const unsigned short* __restrict__ qnh, const unsigned short* __restrict__ qnm,
    const unsigned short* __restrict__ qnl,
    const unsigned short* __restrict__ Wqh, const unsigned short* __restrict__ Wqm,
    const unsigned short* __restrict__ Wql,
    unsigned short* __restrict__ Kah, unsigned short* __restrict__ Kam,
    unsigned short* __restrict__ Kal, unsigned short* __restrict__ Va,
    unsigned short* __restrict__ Qah, unsigned short* __restrict__ Qam,
    unsigned short* __restrict__ Qal,
    const float* __restrict__ fcos, const float* __restrict__ fsin)
{
    __shared__ __align__(16) unsigned short LA[3 * 4096];
    __shared__ __align__(16) unsigned short LB[3 * 4096];
    bool isq = (blockIdx.x >= 16);
    if (!isq)
        gemm3_body(LA, LB, cnh, cnm, cnl, Wuh, Wum, Wul, nullptr,
                   Kah, Kam, Kal, Va, nullptr, nullptr,
                   R_TOT, 2048, 256, 0, 256, 1, blockIdx.y * 128, blockIdx.x * 128);
    else
        gemm3_body(LA, LB, qnh, qnm, qnl, Wqh, Wqm, Wql, nullptr,
                   Qah, Qam, Qal, nullptr, fcos, fsin,
                   R_TOT, 1536, 384, 0, 384, 2, blockIdx.y * 128, (blockIdx.x - 16) * 128);
}

// ---------------------------------------------------------------------------
// 1-plane bf16 GEMM (out-proj), frag-ordered LDS via global_load_lds.
// ---------------------------------------------------------------------------
__global__ __launch_bounds__(256) void gemm_out(
    const unsigned short* __restrict__ Ah, const unsigned short* __restrict__ Bh,
    float* __restrict__ C, int M, int N, int K)
{
    __shared__ __align__(16) unsigned short As[4096];
    __shared__ __align__(16) unsigned short Bs[4096];
    int tid = threadIdx.x;
    int wid = tid >> 6, lane = tid & 63;
    int la = lane & 15, lb = lane >> 4;
    int bm = blockIdx.y * 128, bn = blockIdx.x * 128;
    int wr = (wid >> 1) * 64, wc = (wid & 1) * 64;
    int wr4 = wr >> 4, wc4 = wc >> 4;

    int sg = tid >> 6, spos = tid & 63;
    int rowA0 = (sg << 4) + (spos & 15);
    int rowA1 = ((sg + 4) << 4) + (spos & 15);
    int kc = (spos >> 4) * 8;
    int wb = tid & 192;
    int grA0 = bm + rowA0; if (grA0 >= M) grA0 = M - 1;
    int grA1 = bm + rowA1; if (grA1 >= M) grA1 = M - 1;
    int gnB0 = bn + rowA0; if (gnB0 >= N) gnB0 = N - 1;
    int gnB1 = bn + rowA1; if (gnB1 >= N) gnB1 = N - 1;

    f32x4 acc[4][4];
#pragma unroll
    for (int m = 0; m < 4; ++m)
#pragma unroll
        for (int n = 0; n < 4; ++n) acc[m][n] = (f32x4){0.f, 0.f, 0.f, 0.f};
    for (int k0 = 0; k0 < K; k0 += 32) {
        __syncthreads();
        gl16(Ah + (size_t)grA0 * K + k0 + kc, &As[wb * 8]);
        gl16(Ah + (size_t)grA1 * K + k0 + kc, &As[(256 + wb) * 8]);
        gl16(Bh + (size_t)gnB0 * K + k0 + kc, &Bs[wb * 8]);
        gl16(Bh + (size_t)gnB1 * K + k0 + kc, &Bs[(256 + wb) * 8]);
        __syncthreads();
        bf16x8 a_[4], b_[4];
#pragma unroll
        for (int m = 0; m < 4; ++m) a_[m] = *(const bf16x8*)&As[((wr4 + m) * 64 + lane) * 8];
#pragma unroll
        for (int n = 0; n < 4; ++n) b_[n] = *(const bf16x8*)&Bs[((wc4 + n) * 64 + lane) * 8];
        __builtin_amdgcn_s_setprio(1);
#pragma unroll
        for (int m = 0; m < 4; ++m)
#pragma unroll
            for (int n = 0; n < 4; ++n) acc[m][n] = MFMA(a_[m], b_[n], acc[m][n]);
        __builtin_amdgcn_s_setprio(0);
    }
#pragma unroll
    for (int m = 0; m < 4; ++m)
#pragma unroll
        for (int n = 0; n < 4; ++n) {
            int gc = bn + wc + n * 16 + la;
            if (gc >= N) continue;
#pragma unroll
            for (int r = 0; r < 4; ++r) {
                int gr = bm + wr + m * 16 + lb * 4 + r;
                if (gr < M) C[(size_t)gr * N + gc] = acc[m][n][r];
            }
        }
}

// ---------------------------------------------------------------------------
// RMS-norm both streams (summing the two split-K partials) + K-rope 3-plane.
// ---------------------------------------------------------------------------
__global__ __launch_bounds__(256) void k_rmsrope3(
    const float* __restrict__ ckvqd, const float* __restrict__ ckvqd2,
    unsigned short* __restrict__ cnh, unsigned short* __restrict__ cnm,
    unsigned short* __restrict__ cnl,
    unsigned short* __restrict__ qnh, unsigned short* __restrict__ qnm,
    unsigned short* __restrict__ qnl,
    unsigned short* __restrict__ Kah, unsigned short* __restrict__ Kam,
    unsigned short* __restrict__ Kal,
    const float* __restrict__ gkv, const float* __restrict__ gq,
    const float* __restrict__ fcos, const float* __restrict__ fsin)
{
    __shared__ float red[256];
    __shared__ float rot[32];
    int row = blockIdx.x, tid = threadIdx.x;
    int b = row / SEQ, s = row - b * SEQ;
    const float* cp  = ckvqd  + (size_t)row * 672;
    const float* cp2 = ckvqd2 + (size_t)row * 672;
    float c0 = cp[tid] + cp2[tid];
    float q0 = cp[288 + tid] + cp2[288 + tid];
    float q1 = (tid < 128) ? (cp[544 + tid] + cp2[544 + tid]) : 0.f;

    red[tid] = c0 * c0;
    __syncthreads();
    for (int o = 128; o; o >>= 1) { if (tid < o) red[tid] += red[tid + o]; __syncthreads(); }
    float inv1 = rsqrtf(red[0] * (1.f / 256.f) + EPS_RMS);
    __syncthreads();
    red[tid] = q0 * q0 + q1 * q1;
    __syncthreads();
    for (int o = 128; o; o >>= 1) { if (tid < o) red[tid] += red[tid + o]; __syncthreads(); }
    float inv2 = rsqrtf(red[0] * (1.f / 384.f) + EPS_RMS);

    unsigned short h, m, l;
    split3(c0 * inv1 * gkv[tid], h, m, l);
    size_t ci = (size_t)row * 256 + tid;
    cnh[ci] = h; cnm[ci] = m; cnl[ci] = l;

    split3(q0 * inv2 * gq[tid], h, m, l);
    size_t qi = (size_t)row * 384 + tid;
    qnh[qi] = h; qnm[qi] = m; qnl[qi] = l;
    if (tid < 128) {
        split3(q1 * inv2 * gq[256 + tid], h, m, l);
        qnh[qi + 256] = h; qnm[qi + 256] = m; qnl[qi + 256] = l;
    }

    if (tid < 16) {
        float r0 = cp[256 + 2 * tid] + cp2[256 + 2 * tid];
        float r1 = cp[256 + 2 * tid + 1] + cp2[256 + 2 * tid + 1];
        float o0, o1;
        if (s == 0) { o0 = r0; o1 = r1; }
        else {
            int p = (s - 1) & 255;
            int j = tid & 7;
            float cc = fcos[p * 8 + j], sn = fsin[p * 8 + j];
            o0 = r0 * cc - r1 * sn;
            o1 = r0 * sn + r1 * cc;
        }
        rot[2 * tid] = o0; rot[2 * tid + 1] = o1;
    }
    __syncthreads();
    for (int t = tid; t < 512; t += 256) {
        int H = t >> 4, dd = t & 15;
        int e = H & 1;
        split3(rot[e * 16 + dd], h, m, l);
        size_t idx = (((size_t)b * NH2 + H) * SEQ + s) * 48 + 32 + dd;
        Kah[idx] = h; Kam[idx] = m; Kal[idx] = l;
    }
}

// ---------------------------------------------------------------------------
// MFMA cog-attention v15 = round-17 v12 (verified best structure: linear Pl,
// global pre-transposed V, 0 addressing overhead) + exp2 softmax (log2e
// folded into QSCALE upstream; deletes one v_mul per score element).
// Swizzle dropped: falsified twice (register-pressure cost > conflict win).
// ---------------------------------------------------------------------------
__global__ __launch_bounds__(256, 2) void k_attn15(
    const unsigned short* __restrict__ Qah, const unsigned short* __restrict__ Qam,
    const unsigned short* __restrict__ Qal,
    const unsigned short* __restrict__ Kah, const unsigned short* __restrict__ Kam,
    const unsigned short* __restrict__ Kal,
    const unsigned short* __restrict__ Va, const float* __restrict__ ghead,
    const float* __restrict__ lq1, const float* __restrict__ lk1,
    const float* __restrict__ lq2, const float* __restrict__ lk2,
    unsigned short* __restrict__ attO)
{
    __shared__ __align__(16) unsigned short KS[6][3072];
    __shared__ __align__(16) unsigned short Vt[4096];
    __shared__ __align__(16) unsigned short Pl[4][1024];

    int bid0 = blockIdx.x;
    int bid = (bid0 & 7) * 68 + (bid0 >> 3);   // bijective XCD swizzle (544=8*68)
    int rt = bid % 17;
    int bh = bid / 17;
    int h = bh & 15, b = bh >> 4;
    int tid = threadIdx.x, wid = tid >> 6, lane = tid & 63;
    int la = lane & 15, lb = lane >> 4;
    int r0 = rt * 64, r0w = r0 + wid * 16;

    float e1 = 0.f, e2 = 0.f;
    for (int i = 0; i < 32; ++i) { e1 = fmaf(lq1[i], lk1[i], e1); e2 = fmaf(lq2[i], lk2[i], e2); }
    float lam = __expf(e1) - __expf(e2) + LAMBDA_INIT;

    int pr[4];
#pragma unroll
    for (int g = 0; g < 4; ++g) {
        int r = r0w + lb * 4 + g;
        pr[g] = (r >= 1 && r < SEQ) ? ((r - 1) & 255) : -1;
    }
    int rA = r0w + la;
    int prA = (rA >= 1 && rA < SEQ) ? ((rA - 1) & 255) : -1;

    int prm = -1;
    for (int i = 0; i < 64; ++i) {
        int r = r0 + i;
        if (r >= 1 && r < SEQ) { int p = (r - 1) & 255; prm = p > prm ? p : prm; }
    }

    const size_t hb1 = ((size_t)(b * NH2 + 2 * h)) * SEQ * 48;
    const size_t hb2 = ((size_t)(b * NH2 + 2 * h + 1)) * SEQ * 48;
    const unsigned short* vg = Va + ((size_t)(b * NHEAD + h)) * NVT * 4096;
    const unsigned short* KP[6] = {Kah + hb1, Kam + hb1, Kal + hb1,
                                   Kah + hb2, Kam + hb2, Kal + hb2};

    int qrow = r0w + la; if (qrow > SEQ - 1) qrow = SEQ - 1;
    bf16x8 zf;
#pragma unroll
    for (int u = 0; u < 8; ++u) zf[u] = 0;
    bf16x8 q1[3][2], q2[3][2];
    {
        const unsigned short* QPl[3] = {Qah, Qam, Qal};
#pragma unroll
        for (int p = 0; p < 3; ++p)
#pragma unroll
            for (int f = 0; f < 2; ++f) {
                if (f == 0 || lb < 2) {
                    q1[p][f] = *(const bf16x8*)(QPl[p] + hb1 + (size_t)qrow * 48 + 32 * f + lb * 8);
                    q2[p][f] = *(const bf16x8*)(QPl[p] + hb2 + (size_t)qrow * 48 + 32 * f + lb * 8);
                } else { q1[p][f] = zf; q2[p][f] = zf; }
            }
    }

    // K staging chunk map: ci -> (col, k-octet u)
    int colA, uA, colB = 0, uB = 0;
    {
        int ci = tid;
        colA = ((ci >> 6) << 4) + (ci & 15);
        uA = (ci >> 4) & 3;
        if (tid < 128) {
            int c2 = tid;
            colB = ((c2 >> 5) << 4) + (c2 & 15);
            uB = 4 + ((c2 >> 4) & 1);
        }
    }

    i32x4 preA[6], preB[6], vv[2];
    auto LOADT = [&](int c0n) {
        int gcA = c0n + colA; if (gcA > SEQ - 1) gcA = SEQ - 1;
#pragma unroll
        for (int p = 0; p < 6; ++p)
            preA[p] = *(const i32x4*)(KP[p] + (size_t)gcA * 48 + uA * 8);
        if (tid < 128) {
            int gcB = c0n + colB; if (gcB > SEQ - 1) gcB = SEQ - 1;
#pragma unroll
            for (int p = 0; p < 6; ++p)
                preB[p] = *(const i32x4*)(KP[p] + (size_t)gcB * 48 + uB * 8);
        }
        const unsigned short* vt = vg + (size_t)(c0n >> 6) * 4096;
        vv[0] = *(const i32x4*)(vt + tid * 8);
        vv[1] = *(const i32x4*)(vt + 2048 + tid * 8);
    };
    auto WRITET = [&]() {
#pragma unroll
        for (int p = 0; p < 6; ++p)
            *(i32x4*)&KS[p][tid * 8] = preA[p];          // linear, conflict-free
        if (tid < 128) {
#pragma unroll
            for (int p = 0; p < 6; ++p)
                *(i32x4*)&KS[p][2048 + tid * 8] = preB[p];
        }
        *(i32x4*)&Vt[tid * 8] = vv[0];                   // linear, conflict-free
        *(i32x4*)&Vt[2048 + tid * 8] = vv[1];
    };

    f32x4 O1[4], O2[4], VS[4];
#pragma unroll
    for (int nd = 0; nd < 4; ++nd) {
        O1[nd] = (f32x4){0.f, 0.f, 0.f, 0.f};
        O2[nd] = (f32x4){0.f, 0.f, 0.f, 0.f};
        VS[nd] = (f32x4){0.f, 0.f, 0.f, 0.f};
    }
    float dA1[4] = {0.f, 0.f, 0.f, 0.f}, dA2[4] = {0.f, 0.f, 0.f, 0.f};
    float gsA[4] = {0.f, 0.f, 0.f, 0.f};
    f32x4 z = (f32x4){0.f, 0.f, 0.f, 0.f};

    LOADT(0);
    WRITET();
    __syncthreads();

    for (int j = 0; j <= 16; ++j) {
        bool need = (j == 16) ? (prm >= 255)
                              : (((j & 3) == 0) || (prm >= 64 * (j & 3) - 1));
        if (!need) continue;
        int c0 = j * 64;

        int nj = -1;
        for (int t2 = j + 1; t2 <= 16; ++t2) {
            bool nd2 = (t2 == 16) ? (prm >= 255)
                                  : (((t2 & 3) == 0) || (prm >= 64 * (t2 & 3) - 1));
            if (nd2) { nj = t2; break; }
        }
        if (nj >= 0) LOADT(nj * 64);

        // ---- scores S1 / S2 (packed-layout frag reads) ----
        f32x4 s1[4], s2[4];
        __builtin_amdgcn_s_setprio(1);
#pragma unroll
        for (int n = 0; n < 4; ++n) {
            int g0 = n * 512 + lane * 8;
            int g1 = 2048 + n * 256 + (lane & 31) * 8;
            bf16x8 kh0 = *(const bf16x8*)&KS[0][g0];
            bf16x8 kh1 = *(const bf16x8*)&KS[0][g1];
            bf16x8 km0 = *(const bf16x8*)&KS[1][g0];
            bf16x8 km1 = *(const bf16x8*)&KS[1][g1];
            bf16x8 kl0 = *(const bf16x8*)&KS[2][g0];
            bf16x8 kl1 = *(const bf16x8*)&KS[2][g1];
            f32x4 s = z;
            s = MFMA(q1[0][0], kh0, s); s = MFMA(q1[0][1], kh1, s);
            s = MFMA(q1[0][0], km0, s); s = MFMA(q1[0][1], km1, s);
            s = MFMA(q1[1][0], kh0, s); s = MFMA(q1[1][1], kh1, s);
            s = MFMA(q1[0][0], kl0, s); s = MFMA(q1[0][1], kl1, s);
            s = MFMA(q1[1][0], km0, s); s = MFMA(q1[1][1], km1, s);
            s = MFMA(q1[2][0], kh0, s); s = MFMA(q1[2][1], kh1, s);
            s1[n] = s;
        }
#pragma unroll
        for (int n = 0; n < 4; ++n) {
            int g0 = n * 512 + lane * 8;
            int g1 = 2048 + n * 256 + (lane & 31) * 8;
            bf16x8 kh0 = *(const bf16x8*)&KS[3][g0];
            bf16x8 kh1 = *(const bf16x8*)&KS[3][g1];
            bf16x8 km0 = *(const bf16x8*)&KS[4][g0];
            bf16x8 km1 = *(const bf16x8*)&KS[4][g1];
            bf16x8 kl0 = *(const bf16x8*)&KS[5][g0];
            bf16x8 kl1 = *(const bf16x8*)&KS[5][g1];
            f32x4 s = z;
            s = MFMA(q2[0][0], kh0, s); s = MFMA(q2[0][1], kh1, s);
            s = MFMA(q2[0][0], km0, s); s = MFMA(q2[0][1], km1, s);
            s = MFMA(q2[1][0], kh0, s); s = MFMA(q2[1][1], kh1, s);
            s = MFMA(q2[0][0], kl0, s); s = MFMA(q2[0][1], kl1, s);
            s = MFMA(q2[1][0], km0, s); s = MFMA(q2[1][1], km1, s);
            s = MFMA(q2[2][0], kh0, s); s = MFMA(q2[2][1], kh1, s);
            s2[n] = s;
        }
        __builtin_amdgcn_s_setprio(0);

        // ---- slim no-max signed softmax (exp2; log2e pre-folded into Q) ----
        unsigned short p1v[4][4], p2v[4][4];
#pragma unroll
        for (int n = 0; n < 4; ++n) {
            int c = c0 + n * 16 + la;
            bool cz = (c == 0);
            int cm = (c - 1) & 255;
            bool cin = (c < SEQ);
#pragma unroll
            for (int g = 0; g < 4; ++g) {
                bool al = cz || (cin && cm <= pr[g]);
                float a = s1[n][g];
                float sa = __builtin_copysignf(__builtin_amdgcn_exp2f(fabsf(a)), a);
                sa = al ? sa : 0.f;
                p1v[n][g] = (unsigned short)((__float_as_uint(sa) + 0x8000u) >> 16);
                gsA[g] += sa;
                dA1[g] += fabsf(sa);
                float bb = s2[n][g];
                float sb = __builtin_copysignf(__builtin_amdgcn_exp2f(fabsf(bb)), bb);
                sb = al ? sb : 0.f;
                p2v[n][g] = (unsigned short)((__float_as_uint(sb) + 0x8000u) >> 16);
                dA2[g] += fabsf(sb);
            }
        }

        // ---- P1 -> A-frags via wave-private frag-order LDS ----
#pragma unroll
        for (int n = 0; n < 4; ++n) {
            int pb = (n >> 1) * 512 + (((n & 1) << 1) + (la >> 3)) * 128 + (la & 7);
#pragma unroll
            for (int g = 0; g < 4; ++g)
                Pl[wid][pb + (lb * 4 + g) * 8] = p1v[n][g];
        }
        __asm__ volatile("s_waitcnt lgkmcnt(0)" ::: "memory");
        __builtin_amdgcn_sched_barrier(0);
        bf16x8 p1a0 = *(const bf16x8*)&Pl[wid][lane * 8];
        bf16x8 p1a1 = *(const bf16x8*)&Pl[wid][512 + lane * 8];
#pragma unroll
        for (int n = 0; n < 4; ++n) {
            int pb = (n >> 1) * 512 + (((n & 1) << 1) + (la >> 3)) * 128 + (la & 7);
#pragma unroll
            for (int g = 0; g < 4; ++g)
                Pl[wid][pb + (lb * 4 + g) * 8] = p2v[n][g];
        }
        __asm__ volatile("s_waitcnt lgkmcnt(0)" ::: "memory");
        __builtin_amdgcn_sched_barrier(0);
        bf16x8 p2a0 = *(const bf16x8*)&Pl[wid][lane * 8];
        bf16x8 p2a1 = *(const bf16x8*)&Pl[wid][512 + lane * 8];

        // mask-frags for Vsum
        bf16x8 p0[2];
#pragma unroll
        for (int f = 0; f < 2; ++f)
#pragma unroll
            for (int jb = 0; jb < 8; ++jb) {
                int c = c0 + 32 * f + lb * 8 + jb;
                bool al = (c == 0) || (c < SEQ && ((c - 1) & 255) <= prA);
                p0[f][jb] = al ? (short)0x3F80 : (short)0;
            }

        // ---- PV + VS ----
        __builtin_amdgcn_s_setprio(1);
#pragma unroll
        for (int nd = 0; nd < 4; ++nd) {
            bf16x8 vb0 = *(const bf16x8*)&Vt[(nd * 2) * 512 + lane * 8];
            bf16x8 vb1 = *(const bf16x8*)&Vt[(nd * 2 + 1) * 512 + lane * 8];
            O1[nd] = MFMA(p1a0, vb0, O1[nd]);
            O1[nd] = MFMA(p1a1, vb1, O1[nd]);
            O2[nd] = MFMA(p2a0, vb0, O2[nd]);
            O2[nd] = MFMA(p2a1, vb1, O2[nd]);
            VS[nd] = MFMA(p0[0], vb0, VS[nd]);
            VS[nd] = MFMA(p0[1], vb1, VS[nd]);
        }
        __builtin_amdgcn_s_setprio(0);

        if (nj >= 0) {
            __syncthreads();
            WRITET();
            __syncthreads();
        }
    }

    // ---- final reductions ----
#pragma unroll
    for (int off = 1; off < 16; off <<= 1) {
#pragma unroll
        for (int g = 0; g < 4; ++g) {
            dA1[g] += __shfl_xor(dA1[g], off);
            dA2[g] += __shfl_xor(dA2[g], off);
            gsA[g] += __shfl_xor(gsA[g], off);
        }
    }

    float i1[4], i2g[4], Gl[4];
#pragma unroll
    for (int g = 0; g < 4; ++g) {
        i1[g] = 1.f / dA1[g];
        i2g[g] = 1.f / dA2[g];
        Gl[g] = gsA[g] * i1[g] * (1.f / (float)SEQ) * lam;
    }
    f32x4 outv[4];
#pragma unroll
    for (int nd = 0; nd < 4; ++nd)
#pragma unroll
        for (int g = 0; g < 4; ++g)
            outv[nd][g] = O1[nd][g] * i1[g] - lam * i2g[g] * O2[nd][g] + Gl[g] * VS[nd][g];

    float ssq[4] = {0.f, 0.f, 0.f, 0.f};
#pragma unroll
    for (int nd = 0; nd < 4; ++nd)
#pragma unroll
        for (int g = 0; g < 4; ++g) ssq[g] += outv[nd][g] * outv[nd][g];
#pragma unroll
    for (int off = 1; off < 16; off <<= 1)
#pragma unroll
        for (int g = 0; g < 4; ++g) ssq[g] += __shfl_xor(ssq[g], off);
    float inv[4];
#pragma unroll
    for (int g = 0; g < 4; ++g) inv[g] = rsqrtf(ssq[g] * (1.f / 64.f) + EPS_HEAD);

#pragma unroll
    for (int nd = 0; nd < 4; ++nd) {
        int d = nd * 16 + la;
        float gv = ghead[d];
#pragma unroll
        for (int g = 0; g < 4; ++g) {
            int r = r0w + lb * 4 + g;
            if (r < SEQ)
                attO[(((size_t)b * SEQ + r) * NHEAD + h) * 64 + d] =
                    f2bf(outv[nd][g] * inv[g] * gv);
        }
    }
}

// ---------------------------------------------------------------------------
extern "C" void kernel_launch(void* const* d_in, const int* in_sizes, int n_in,
                              void* d_out, int out_size, void* d_ws, size_t ws_size,
                              hipStream_t stream)
{
    const float* x    = (const float*)d_in[0];
    const float* fcos = (const float*)d_in[2];
    const float* fsin = (const float*)d_in[3];
    const float* Wkvd = (const float*)d_in[4];
    const float* Wqd  = (const float*)d_in[5];
    const float* Wkvu = (const float*)d_in[6];
    const float* Wqu  = (const float*)d_in[7];
    const float* Wo   = (const float*)d_in[8];
    const float* gkv  = (const float*)d_in[9];
    const float* gq   = (const float*)d_in[10];
    const float* gh   = (const float*)d_in[11];
    const float* lq1  = (const float*)d_in[12];
    const float* lk1  = (const float*)d_in[13];
    const float* lq2  = (const float*)d_in[14];
    const float* lk2  = (const float*)d_in[15];
    float* out = (float*)d_out;

    const int R = R_TOT;  // 2050
    char* base = (char*)d_ws;
    size_t off = 0;
    auto alloc = [&](size_t bytes) -> char* {
        char* p = base + off;
        off = (off + bytes + 255) & ~(size_t)255;
        return p;
    };
    const size_t KPL = (size_t)BATCH * NH2 * SEQ * 48 * 2;   // per K/Q plane
    const size_t VAB = (size_t)BATCH * NHEAD * NVT * 4096 * 2;  // tiled Vt

    unsigned short* xh = (unsigned short*)alloc((size_t)R * 1024 * 2);
    unsigned short* xm = (unsigned short*)alloc((size_t)R * 1024 * 2);
    unsigned short* xl = (unsigned short*)alloc((size_t)R * 1024 * 2);
    unsigned short* attO = xh;                      // x dead after down-GEMM
    unsigned short* Kah  = xm;                      // KPL fits xm+xl

    float* ckvqd = (float*)alloc((size_t)R * 672 * 4);
    unsigned short* cnh = (unsigned short*)alloc((size_t)R * 256 * 2);
    unsigned short* cnm = (unsigned short*)alloc((size_t)R * 256 * 2);
    unsigned short* cnl = (unsigned short*)alloc((size_t)R * 256 * 2);
    unsigned short* qnh = (unsigned short*)alloc((size_t)R * 384 * 2);
    unsigned short* qnm = (unsigned short*)alloc((size_t)R * 384 * 2);
    unsigned short* qnl = (unsigned short*)alloc((size_t)R * 384 * 2);
    unsigned short* Kam = (unsigned short*)alloc(KPL);
    unsigned short* Kal = (unsigned short*)alloc(KPL);
    unsigned short* Qah = (unsigned short*)alloc(KPL);
    unsigned short* Qam = (unsigned short*)alloc(KPL);
    unsigned short* Qal = (unsigned short*)alloc(KPL);
    unsigned short* Va  = (unsigned short*)alloc(VAB);
    unsigned short* Wdh = (unsigned short*)alloc((size_t)672 * 1024 * 2);
    unsigned short* Wdm = (unsigned short*)alloc((size_t)672 * 1024 * 2);
    unsigned short* Wdl = (unsigned short*)alloc((size_t)672 * 1024 * 2);
    unsigned short* Wuh = (unsigned short*)alloc((size_t)2048 * 256 * 2);
    unsigned short* Wum = (unsigned short*)alloc((size_t)2048 * 256 * 2);
    unsigned short* Wul = (unsigned short*)alloc((size_t)2048 * 256 * 2);
    unsigned short* Wqh = (unsigned short*)alloc((size_t)1536 * 384 * 2);
    unsigned short* Wqm = (unsigned short*)alloc((size_t)1536 * 384 * 2);
    unsigned short* Wql = (unsigned short*)alloc((size_t)1536 * 384 * 2);
    unsigned short* Wo1 = (unsigned short*)alloc((size_t)1024 * 1024 * 2);

    // split-K partial #2 for down-proj: aliases Qah (dead until gemm_up).
    float* ckvqd2 = (float*)Qah;

    dim3 blk(256);
    conv_all<<<4834, blk, 0, stream>>>(x, Wkvd, Wqd, Wkvu, Wqu, Wo,
        xh, xm, xl, Wdh, Wdm, Wdl, Wuh, Wum, Wul, Wqh, Wqm, Wql, Wo1);
    gemm_down<<<dim3(6, 17, 2), blk, 0, stream>>>(xh, xm, xl, Wdh, Wdm, Wdl,
                                                  ckvqd, ckvqd2);
    k_rmsrope3<<<R, blk, 0, stream>>>(ckvqd, ckvqd2, cnh, cnm, cnl, qnh, qnm, qnl,
                                      Kah, Kam, Kal, gkv, gq, fcos, fsin);
    // zero Va so tile-16 padding cols (>=SEQ) are 0 (they multiply P=0 anyway)
    hipMemsetAsync(Va, 0, VAB, stream);
    gemm_up<<<dim3(28, 17), blk, 0, stream>>>(cnh, cnm, cnl, Wuh, Wum, Wul,
        qnh, qnm, qnl, Wqh, Wqm, Wql, Kah, Kam, Kal, Va, Qah, Qam, Qal, fcos, fsin);
    k_attn15<<<544, blk, 0, stream>>>(Qah, Qam, Qal, Kah, Kam, Kal,
        Va, gh, lq1, lk1, lq2, lk2, attO);
    gemm_out<<<dim3(8, 17), blk, 0, stream>>>(attO, Wo1, out, R, 1024, 1024);
}